// Round 2
// baseline (3801.682 us; speedup 1.0000x reference)
//
#include <hip/hip_runtime.h>
#include <math.h>

// Dims: N=128, C=128, T=64, V=25, S=3, R=32; TV=1600, CTV=204800, QKTV=307200.
// Big intermediates (qk, y1, z9) are stored as bf16 bits (ushort) in d_ws;
// all arithmetic is fp32.

__device__ __forceinline__ ushort f2bf(float f) {
    uint b = __float_as_uint(f);
    uint r = b + 0x7fffu + ((b >> 16) & 1u);
    return (ushort)(r >> 16);
}
__device__ __forceinline__ float bf2f(ushort h) {
    return __uint_as_float(((uint)h) << 16);
}

__global__ __launch_bounds__(256) void qk_pe_kernel(
    const float* __restrict__ src, const float* __restrict__ W,
    const float* __restrict__ bias, ushort* __restrict__ out, int pos_is_t)
{
    __shared__ float xs[128][100];
    const int n = blockIdx.y;
    const int tv0 = blockIdx.x * 100;
    const float* sn = src + (size_t)n * 204800;
    for (int i = threadIdx.x; i < 3200; i += 256) {
        int c = i / 25, col4 = i - c * 25;
        float4 xv = *(const float4*)(sn + c * 1600 + tv0 + col4 * 4);
        float dv = __expf(-0.14391156831212787f * (float)(c >> 1)); // ln(1e4)/64
        float pe4[4];
        float xin[4] = { xv.x, xv.y, xv.z, xv.w };
#pragma unroll
        for (int e = 0; e < 4; e++) {
            int tv = tv0 + col4 * 4 + e;
            float pos = pos_is_t ? (float)(tv / 25) : (float)(tv % 25);
            float ang = pos * dv;
            pe4[e] = (c & 1) ? __cosf(ang) : __sinf(ang);
        }
        float* dst = &xs[c][col4 * 4];
#pragma unroll
        for (int e = 0; e < 4; e++) dst[e] = xin[e] + pe4[e];
    }
    __syncthreads();
    const int r  = threadIdx.x >> 2;   // 0..63
    const int cg = threadIdx.x & 3;    // 0..3
    float acc0[25], acc1[25], acc2[25];
#pragma unroll
    for (int j = 0; j < 25; j++) { acc0[j] = 0.f; acc1[j] = 0.f; acc2[j] = 0.f; }
    const float* w0 = W + r * 128;
    const float* w1 = W + (r + 64) * 128;
    const float* w2 = W + (r + 128) * 128;
#pragma unroll 4
    for (int c = 0; c < 128; c++) {
        float a0 = w0[c], a1 = w1[c], a2 = w2[c];
        const float* xr = &xs[c][cg * 25];
#pragma unroll
        for (int j = 0; j < 25; j++) {
            float xv = xr[j];
            acc0[j] += a0 * xv; acc1[j] += a1 * xv; acc2[j] += a2 * xv;
        }
    }
    float b0 = bias[r], b1 = bias[r + 64], b2 = bias[r + 128];
    ushort* o0 = out + (size_t)n * 307200 + r * 1600 + tv0 + cg * 25;
    ushort* o1 = o0 + 64 * 1600;
    ushort* o2 = o0 + 128 * 1600;
#pragma unroll
    for (int j = 0; j < 25; j++) {
        o0[j] = f2bf(acc0[j] + b0);
        o1[j] = f2bf(acc1[j] + b1);
        o2[j] = f2bf(acc2[j] + b2);
    }
}

// att_s[u,v] = tanh( sum_{r<32,t<64} q[r,t,u]*k[r,t,v] / 2048 )*alpha[s] + att0[s,u,v]
__global__ __launch_bounds__(128) void att_s_kernel(
    const ushort* __restrict__ qk, const float* __restrict__ alphas,
    const float* __restrict__ att0, float* __restrict__ attOut)
{
    __shared__ float sm[2 * 32 * 404];
    float* qs = sm;             // [32][404]
    float* ks = sm + 32 * 404;  // [32][404]
    const int s = blockIdx.x, n = blockIdx.y;
    const ushort* qkn = qk + (size_t)n * 307200;
    const int ut = threadIdx.x >> 3; // 0..15 (13 used)
    const int rg = threadIdx.x & 7;
    const int u0 = ut * 2, u1 = u0 + 1;
    float acc0[25], acc1[25];
#pragma unroll
    for (int v = 0; v < 25; v++) { acc0[v] = 0.f; acc1[v] = 0.f; }
    for (int tc = 0; tc < 4; tc++) {
        __syncthreads();
        for (int i = threadIdx.x; i < 6400; i += 128) {
            int r = i / 200, col2 = i - r * 200;
            uint uq = *(const uint*)(qkn + (s * 32 + r) * 1600 + tc * 400 + col2 * 2);
            uint uk = *(const uint*)(qkn + (96 + s * 32 + r) * 1600 + tc * 400 + col2 * 2);
            qs[r * 404 + col2 * 2]     = __uint_as_float((uq & 0xffffu) << 16);
            qs[r * 404 + col2 * 2 + 1] = __uint_as_float(uq & 0xffff0000u);
            ks[r * 404 + col2 * 2]     = __uint_as_float((uk & 0xffffu) << 16);
            ks[r * 404 + col2 * 2 + 1] = __uint_as_float(uk & 0xffff0000u);
        }
        __syncthreads();
        if (ut < 13) {
            const int uu1 = (u1 < 25) ? u1 : 0;
#pragma unroll
            for (int rr = 0; rr < 4; rr++) {
                int r = rg * 4 + rr;
                for (int t = 0; t < 16; t++) {
                    float qa = qs[r * 404 + t * 25 + u0];
                    float qb = qs[r * 404 + t * 25 + uu1];
                    const float* kr = &ks[r * 404 + t * 25];
#pragma unroll
                    for (int v = 0; v < 25; v++) {
                        float kv = kr[v];
                        acc0[v] += qa * kv; acc1[v] += qb * kv;
                    }
                }
            }
        }
    }
    __syncthreads();
    float* red = sm; // [8][650] overlay on qs
    if (ut < 13) {
#pragma unroll
        for (int v = 0; v < 25; v++) red[rg * 650 + u0 * 25 + v] = acc0[v];
        if (u1 < 25) {
#pragma unroll
            for (int v = 0; v < 25; v++) red[rg * 650 + u1 * 25 + v] = acc1[v];
        }
    }
    __syncthreads();
    float alpha = alphas[s];
    for (int i = threadIdx.x; i < 625; i += 128) {
        float sum = 0.f;
#pragma unroll
        for (int g = 0; g < 8; g++) sum += red[g * 650 + i];
        attOut[(size_t)(n * 3 + s) * 625 + i] =
            tanhf(sum * (1.0f / 2048.0f)) * alpha + att0[s * 625 + i];
    }
}

// att_t[t,q] = tanh( sum_{r<32,v<25} q[r,t,v]*k[r,q,v] / 800 )*alpha[s] + att0[s,t,q]
__global__ __launch_bounds__(128) void att_t_kernel(
    const ushort* __restrict__ qk, const float* __restrict__ alphat,
    const float* __restrict__ att0, float* __restrict__ attOut)
{
    __shared__ float sm[2 * 13600];
    float* qst = sm;            // [8][25][68] (v-major, padded)
    float* kst = sm + 13600;
    const int s = blockIdx.x, n = blockIdx.y;
    const ushort* qkn = qk + (size_t)n * 307200;
    const int tg = threadIdx.x & 15;
    const int qg = (threadIdx.x >> 4) & 3;
    const int rh = threadIdx.x >> 6;
    const int t0 = tg * 4, q0 = qg * 16;
    float acc[4][16];
#pragma unroll
    for (int i = 0; i < 4; i++)
#pragma unroll
        for (int jj = 0; jj < 16; jj++) acc[i][jj] = 0.f;
    for (int rc = 0; rc < 4; rc++) {
        __syncthreads();
        for (int i = threadIdx.x; i < 6400; i += 128) {
            int rr = i / 800; int rem2 = (i - rr * 800) * 2;
            uint uq = *(const uint*)(qkn + (s * 32 + rc * 8 + rr) * 1600 + rem2);
            uint uk = *(const uint*)(qkn + (96 + s * 32 + rc * 8 + rr) * 1600 + rem2);
            int ta = rem2 / 25, va = rem2 - ta * 25;
            int tb = (rem2 + 1) / 25, vb = (rem2 + 1) - tb * 25;
            qst[rr * 1700 + va * 68 + ta] = __uint_as_float((uq & 0xffffu) << 16);
            qst[rr * 1700 + vb * 68 + tb] = __uint_as_float(uq & 0xffff0000u);
            kst[rr * 1700 + va * 68 + ta] = __uint_as_float((uk & 0xffffu) << 16);
            kst[rr * 1700 + vb * 68 + tb] = __uint_as_float(uk & 0xffff0000u);
        }
        __syncthreads();
#pragma unroll
        for (int rr = 0; rr < 4; rr++) {
            int r = rh * 4 + rr;
            for (int v = 0; v < 25; v++) {
                float4 qv = *(const float4*)&qst[r * 1700 + v * 68 + t0];
                const float4* kp = (const float4*)&kst[r * 1700 + v * 68 + q0];
                float qa[4] = { qv.x, qv.y, qv.z, qv.w };
#pragma unroll
                for (int b = 0; b < 4; b++) {
                    float4 kv = kp[b];
#pragma unroll
                    for (int i = 0; i < 4; i++) {
                        acc[i][b * 4 + 0] += qa[i] * kv.x;
                        acc[i][b * 4 + 1] += qa[i] * kv.y;
                        acc[i][b * 4 + 2] += qa[i] * kv.z;
                        acc[i][b * 4 + 3] += qa[i] * kv.w;
                    }
                }
            }
        }
    }
    __syncthreads();
    float* red = sm; // [2][4096] overlay
#pragma unroll
    for (int i = 0; i < 4; i++)
#pragma unroll
        for (int jj = 0; jj < 16; jj++)
            red[rh * 4096 + (t0 + i) * 64 + q0 + jj] = acc[i][jj];
    __syncthreads();
    float alpha = alphat[s];
    for (int i = threadIdx.x; i < 4096; i += 128) {
        float sum = red[i] + red[4096 + i];
        attOut[(size_t)(n * 3 + s) * 4096 + i] =
            tanhf(sum * (1.0f / 800.0f)) * alpha + att0[s * 4096 + i];
    }
}

// y1 = lrelu(x + BN(Wo_s @ y2 + bo)),  y2[s,c,t,v] = sum_u x[c,t,u]*attS[s,u,v]
__global__ __launch_bounds__(256) void fused_spatial(
    const float* __restrict__ x, const float* __restrict__ attS,
    const float* __restrict__ Wo, const float* __restrict__ bo,
    const float* __restrict__ bnp, ushort* __restrict__ y1)
{
    __shared__ float xs[128][100];
    __shared__ float y2s[128][100];
    __shared__ float attm[1875];
    const int n = blockIdx.y, tv0 = blockIdx.x * 100;
    const float* xn = x + (size_t)n * 204800;
    for (int i = threadIdx.x; i < 3200; i += 256) {
        int c = i / 25, col4 = i - c * 25;
        *(float4*)&xs[c][col4 * 4] = *(const float4*)(xn + c * 1600 + tv0 + col4 * 4);
    }
    for (int i = threadIdx.x; i < 1875; i += 256) attm[i] = attS[(size_t)n * 1875 + i];
    __syncthreads();
    const int op = threadIdx.x >> 2, cg = threadIdx.x & 3;
    float acc0[25], acc1[25];
#pragma unroll
    for (int j = 0; j < 25; j++) { acc0[j] = 0.f; acc1[j] = 0.f; }
    for (int s = 0; s < 3; s++) {
        for (int i = threadIdx.x; i < 512; i += 256) {
            int c = i >> 2, t = i & 3;
            float av[25];
#pragma unroll
            for (int v = 0; v < 25; v++) av[v] = 0.f;
            const float* xrow = &xs[c][t * 25];
            const float* am = &attm[s * 625];
            for (int u = 0; u < 25; u++) {
                float xv = xrow[u];
#pragma unroll
                for (int v = 0; v < 25; v++) av[v] += xv * am[u * 25 + v];
            }
            float* yr = &y2s[c][t * 25];
#pragma unroll
            for (int v = 0; v < 25; v++) yr[v] = av[v];
        }
        __syncthreads();
        const float* w0p = Wo + op * 384 + s * 128;
        const float* w1p = Wo + (op + 64) * 384 + s * 128;
#pragma unroll 2
        for (int c = 0; c < 128; c++) {
            float w0 = w0p[c], w1 = w1p[c];
            const float* yr = &y2s[c][cg * 25];
#pragma unroll
            for (int j = 0; j < 25; j++) {
                float yv = yr[j];
                acc0[j] += w0 * yv; acc1[j] += w1 * yv;
            }
        }
        __syncthreads();
    }
    {
        int o = op;
        float inv = bnp[o] * rsqrtf(bnp[384 + o] + 1e-5f);
        float bet = bnp[128 + o], mu = bnp[256 + o], bb = bo[o];
        ushort* outp = y1 + (size_t)n * 204800 + o * 1600 + tv0 + cg * 25;
        const float* xr = &xs[o][cg * 25];
#pragma unroll
        for (int j = 0; j < 25; j++) {
            float h = (acc0[j] + bb - mu) * inv + bet;
            float rr = xr[j] + h;
            outp[j] = f2bf(rr > 0.f ? rr : 0.1f * rr);
        }
    }
    {
        int o = op + 64;
        float inv = bnp[o] * rsqrtf(bnp[384 + o] + 1e-5f);
        float bet = bnp[128 + o], mu = bnp[256 + o], bb = bo[o];
        ushort* outp = y1 + (size_t)n * 204800 + o * 1600 + tv0 + cg * 25;
        const float* xr = &xs[o][cg * 25];
#pragma unroll
        for (int j = 0; j < 25; j++) {
            float h = (acc1[j] + bb - mu) * inv + bet;
            float rr = xr[j] + h;
            outp[j] = f2bf(rr > 0.f ? rr : 0.1f * rr);
        }
    }
}

// z9 = lrelu(y + BN(Wo_t @ z2 + bo)),  z2[s,c,q,v] = sum_t y[c,t,v]*attT[s,t,q]
__global__ __launch_bounds__(256) void fused_temporal(
    const float* __restrict__ y, const float* __restrict__ attT,
    const float* __restrict__ Wo, const float* __restrict__ bo,
    const float* __restrict__ bnp, ushort* __restrict__ z9)
{
    __shared__ float ys[16][1604];
    __shared__ float z2c[3 * 16 * 100];
    __shared__ float attm[768]; // [s][t][qq]
    const int n = blockIdx.y, q0 = blockIdx.x * 4;
    const float* yn = y + (size_t)n * 204800;
    for (int i = threadIdx.x; i < 768; i += 256) {
        int s = i >> 8; int rem = i & 255; int t = rem >> 2; int qq = rem & 3;
        attm[i] = attT[(size_t)(n * 3 + s) * 4096 + t * 64 + q0 + qq];
    }
    const int op = threadIdx.x >> 2, cg = threadIdx.x & 3;
    float acc0[25], acc1[25];
#pragma unroll
    for (int j = 0; j < 25; j++) { acc0[j] = 0.f; acc1[j] = 0.f; }
    for (int cc = 0; cc < 8; cc++) {
        for (int i = threadIdx.x; i < 6400; i += 256) {
            int ci = i / 400, col4 = i - ci * 400;
            *(float4*)&ys[ci][col4 * 4] =
                *(const float4*)(yn + (size_t)(cc * 16 + ci) * 1600 + col4 * 4);
        }
        __syncthreads();
        if (threadIdx.x < 192) {
            int ci = threadIdx.x / 12, sq = threadIdx.x % 12, s = sq >> 2, qq = sq & 3;
            float av[25];
#pragma unroll
            for (int v = 0; v < 25; v++) av[v] = 0.f;
            for (int t = 0; t < 64; t++) {
                float a = attm[s * 256 + t * 4 + qq];
                const float* yr = &ys[ci][t * 25];
#pragma unroll
                for (int v = 0; v < 25; v++) av[v] += yr[v] * a;
            }
            float* zr = &z2c[(s * 16 + ci) * 100 + qq * 25];
#pragma unroll
            for (int v = 0; v < 25; v++) zr[v] = av[v];
        }
        __syncthreads();
#pragma unroll 2
        for (int k = 0; k < 48; k++) {
            int s = k / 16, ci = k - s * 16;
            int c = s * 128 + cc * 16 + ci;
            float w0 = Wo[op * 384 + c], w1 = Wo[(op + 64) * 384 + c];
            const float* zr = &z2c[(s * 16 + ci) * 100 + cg * 25];
#pragma unroll
            for (int j = 0; j < 25; j++) {
                float zv = zr[j];
                acc0[j] += w0 * zv; acc1[j] += w1 * zv;
            }
        }
        __syncthreads();
    }
    {
        int o = op;
        float inv = bnp[o] * rsqrtf(bnp[384 + o] + 1e-5f);
        float bet = bnp[128 + o], mu = bnp[256 + o], bb = bo[o];
        const float* resp = yn + o * 1600 + (q0 + cg) * 25;
        ushort* outp = z9 + (size_t)n * 204800 + o * 1600 + (q0 + cg) * 25;
#pragma unroll
        for (int j = 0; j < 25; j++) {
            float h = (acc0[j] + bb - mu) * inv + bet;
            float rr = resp[j] + h;
            outp[j] = f2bf(rr > 0.f ? rr : 0.1f * rr);
        }
    }
    {
        int o = op + 64;
        float inv = bnp[o] * rsqrtf(bnp[384 + o] + 1e-5f);
        float bet = bnp[128 + o], mu = bnp[256 + o], bb = bo[o];
        const float* resp = yn + o * 1600 + (q0 + cg) * 25;
        ushort* outp = z9 + (size_t)n * 204800 + o * 1600 + (q0 + cg) * 25;
#pragma unroll
        for (int j = 0; j < 25; j++) {
            float h = (acc1[j] + bb - mu) * inv + bet;
            float rr = resp[j] + h;
            outp[j] = f2bf(rr > 0.f ? rr : 0.1f * rr);
        }
    }
}

// out = lrelu(res + BN(W @ in + bias)); res/out may alias (element-wise per thread).
__global__ __launch_bounds__(256) void conv_bn_res(
    const ushort* __restrict__ in, const float* res,
    const float* __restrict__ W, const float* __restrict__ bias,
    const float* __restrict__ bnp, float* out)
{
    __shared__ float ins[128][100];
    const int n = blockIdx.y, tv0 = blockIdx.x * 100;
    const ushort* inn = in + (size_t)n * 204800;
    for (int i = threadIdx.x; i < 6400; i += 256) {
        int c = i / 50, col2 = i - c * 50;
        uint u = *(const uint*)(inn + c * 1600 + tv0 + col2 * 2);
        ins[c][col2 * 2]     = __uint_as_float((u & 0xffffu) << 16);
        ins[c][col2 * 2 + 1] = __uint_as_float(u & 0xffff0000u);
    }
    __syncthreads();
    const int op = threadIdx.x >> 2, cg = threadIdx.x & 3;
    float acc0[25], acc1[25];
#pragma unroll
    for (int j = 0; j < 25; j++) { acc0[j] = 0.f; acc1[j] = 0.f; }
    const float* w0p = W + op * 128;
    const float* w1p = W + (op + 64) * 128;
#pragma unroll 4
    for (int c = 0; c < 128; c++) {
        float w0 = w0p[c], w1 = w1p[c];
        const float* xr = &ins[c][cg * 25];
#pragma unroll
        for (int j = 0; j < 25; j++) {
            float v = xr[j];
            acc0[j] += w0 * v; acc1[j] += w1 * v;
        }
    }
    {
        int o = op;
        float inv = bnp[o] * rsqrtf(bnp[384 + o] + 1e-5f);
        float bet = bnp[128 + o], mu = bnp[256 + o], bb = bias[o];
        const float* r0 = res + (size_t)n * 204800 + o * 1600 + tv0 + cg * 25;
        float* o0 = out + (size_t)n * 204800 + o * 1600 + tv0 + cg * 25;
#pragma unroll
        for (int j = 0; j < 25; j++) {
            float h = (acc0[j] + bb - mu) * inv + bet;
            float rr = r0[j] + h;
            o0[j] = rr > 0.f ? rr : 0.1f * rr;
        }
    }
    {
        int o = op + 64;
        float inv = bnp[o] * rsqrtf(bnp[384 + o] + 1e-5f);
        float bet = bnp[128 + o], mu = bnp[256 + o], bb = bias[o];
        const float* r1 = res + (size_t)n * 204800 + o * 1600 + tv0 + cg * 25;
        float* o1 = out + (size_t)n * 204800 + o * 1600 + tv0 + cg * 25;
#pragma unroll
        for (int j = 0; j < 25; j++) {
            float h = (acc1[j] + bb - mu) * inv + bet;
            float rr = r1[j] + h;
            o1[j] = rr > 0.f ? rr : 0.1f * rr;
        }
    }
}

extern "C" void kernel_launch(void* const* d_in, const int* in_sizes, int n_in,
                              void* d_out, int out_size, void* d_ws, size_t ws_size,
                              hipStream_t stream)
{
    (void)in_sizes; (void)n_in; (void)out_size; (void)ws_size;
    const float* x      = (const float*)d_in[0];
    const float* Wqk_s  = (const float*)d_in[1];
    const float* bqk_s  = (const float*)d_in[2];
    const float* alphas = (const float*)d_in[3];
    const float* att0s  = (const float*)d_in[4];
    const float* Wo_s   = (const float*)d_in[5];
    const float* bo_s   = (const float*)d_in[6];
    const float* bn_o_s = (const float*)d_in[7];
    const float* Wf_s   = (const float*)d_in[8];
    const float* bf_s   = (const float*)d_in[9];
    const float* bn_f_s = (const float*)d_in[10];
    const float* Wqk_t  = (const float*)d_in[11];
    const float* bqk_t  = (const float*)d_in[12];
    const float* alphat = (const float*)d_in[13];
    const float* att0t  = (const float*)d_in[14];
    const float* Wo_t   = (const float*)d_in[15];
    const float* bo_t   = (const float*)d_in[16];
    const float* bn_o_t = (const float*)d_in[17];
    const float* Wf_t   = (const float*)d_in[18];
    const float* bf_t   = (const float*)d_in[19];
    const float* bn_f_t = (const float*)d_in[20];

    float* out  = (float*)d_out;
    // ws layout (bytes): [0, 78,643,200) bf16 big (qk / y1 / z9 reused)
    //                    [78,643,200, 79,603,200) attS fp32
    //                    [79,603,200, 85,894,656) attT fp32
    ushort* big = (ushort*)d_ws;
    float* attS = (float*)((char*)d_ws + 78643200);
    float* attT = attS + 240000;

    dim3 g16(16, 128);
    dim3 gatt(3, 128);

    // ---- spatial ----
    qk_pe_kernel<<<g16, 256, 0, stream>>>(x, Wqk_s, bqk_s, big, 0);
    att_s_kernel<<<gatt, 128, 0, stream>>>(big, alphas, att0s, attS);
    fused_spatial<<<g16, 256, 0, stream>>>(x, attS, Wo_s, bo_s, bn_o_s, big);   // y1 -> big
    conv_bn_res<<<g16, 256, 0, stream>>>(big, x, Wf_s, bf_s, bn_f_s, out);      // y  -> d_out

    // ---- temporal ----
    qk_pe_kernel<<<g16, 256, 0, stream>>>(out, Wqk_t, bqk_t, big, 1);
    att_t_kernel<<<gatt, 128, 0, stream>>>(big, alphat, att0t, attT);
    fused_temporal<<<g16, 256, 0, stream>>>(out, attT, Wo_t, bo_t, bn_o_t, big); // z9 -> big
    conv_bn_res<<<g16, 256, 0, stream>>>(big, out, Wf_t, bf_t, bn_f_t, out);     // z  -> d_out (in-place res)
}

// Round 3
// 2859.134 us; speedup vs baseline: 1.3297x; 1.3297x over previous
//
#include <hip/hip_runtime.h>
#include <math.h>

// Dims: N=128, C=128, T=64, V=25, S=3, R=32; TV=1600, CTV=204800.
// Reordered algebra:
//   spatial: y1[o,t,v] = lrelu(x + BN(sum_{s,u} attS[s,u,v] * H[o,s,t,u]))
//            H[o,s,t,u] = sum_c Wo_s[o,s*128+c] * x[c,t,u]          (T1 kernel)
//   temporal: z9[o,q,v] = lrelu(y + BN(sum_{s,t} attT[s,t,q] * G[o,s,t,v]))
//            G[o,s,t,v] = sum_c Wo_t[o,s*128+c] * y[c,t,v]          (T1 kernel)
// G/H stored bf16 as [n'][s][t][v][128o] (o fastest -> coalesced stores).
// Processed in 4 quarters of 32 n to fit workspace.

__device__ __forceinline__ ushort f2bf(float f) {
    uint b = __float_as_uint(f);
    uint r = b + 0x7fffu + ((b >> 16) & 1u);
    return (ushort)(r >> 16);
}

__device__ __forceinline__ void fma25(float (&acc)[25], float w, const float* yy) {
#pragma unroll
    for (int jb = 0; jb < 6; jb++) {
        float4 q = *(const float4*)(yy + jb * 4);
        acc[jb*4+0] += w * q.x; acc[jb*4+1] += w * q.y;
        acc[jb*4+2] += w * q.z; acc[jb*4+3] += w * q.w;
    }
    acc[24] += w * yy[24];
}

__device__ __forceinline__ void fma25r(float* acc, float a, const float* g) {
#pragma unroll
    for (int v = 0; v < 25; v++) acc[v] += a * g[v];
}

// ---------------- weight transposes (runs once per call, tiny) ----------------
__global__ __launch_bounds__(256) void wt_prep(
    const float* __restrict__ Wo_s, const float* __restrict__ Wf_s,
    const float* __restrict__ Wo_t, const float* __restrict__ Wf_t,
    const float* __restrict__ Wqk_s, const float* __restrict__ Wqk_t,
    float* __restrict__ WT)
{
    int idx = blockIdx.x * 256 + threadIdx.x;
    if (idx >= 180224) return;
    if (idx < 49152) {                       // WToS[s][c][o]
        int s = idx / 16384, rem = idx % 16384, c = rem / 128, o = rem % 128;
        WT[idx] = Wo_s[o * 384 + s * 128 + c];
    } else if (idx < 65536) {                // WTfS[c][o]
        int i = idx - 49152, c = i / 128, o = i % 128;
        WT[idx] = Wf_s[o * 128 + c];
    } else if (idx < 114688) {               // WToT
        int i = idx - 65536, s = i / 16384, rem = i % 16384, c = rem / 128, o = rem % 128;
        WT[idx] = Wo_t[o * 384 + s * 128 + c];
    } else if (idx < 131072) {               // WTfT
        int i = idx - 114688, c = i / 128, o = i % 128;
        WT[idx] = Wf_t[o * 128 + c];
    } else if (idx < 155648) {               // WTqkS[c][r]
        int i = idx - 131072, c = i / 192, r = i % 192;
        WT[idx] = Wqk_s[r * 128 + c];
    } else {                                 // WTqkT[c][r]
        int i = idx - 155648, c = i / 192, r = i % 192;
        WT[idx] = Wqk_t[r * 128 + c];
    }
}

// ---------------- qk = Wqk @ (x + PE), bf16 out [n][192][1600] ----------------
__global__ __launch_bounds__(256) void qk_pe_v2(
    const float* __restrict__ src, const float* __restrict__ WT, // [128c][192r]
    const float* __restrict__ bias, ushort* __restrict__ out, int pos_is_t)
{
    __shared__ float xs[128 * 4 * 28];   // [c][t_local][25 (+3 pad)]
    __shared__ float buf[32 * 4 * 25];   // store-exchange
    const int n = blockIdx.y, tv0 = blockIdx.x * 100;
    const float* sn = src + (size_t)n * 204800;
    for (int i = threadIdx.x; i < 3200; i += 256) {
        int c = i / 25, col4 = i - c * 25;
        float4 xv = *(const float4*)(sn + c * 1600 + tv0 + col4 * 4);
        float dv = __expf(-0.14391156831212787f * (float)(c >> 1)); // ln(1e4)/64
        float vals[4] = { xv.x, xv.y, xv.z, xv.w };
#pragma unroll
        for (int e = 0; e < 4; e++) {
            int col = col4 * 4 + e;
            int tv = tv0 + col;
            int tt = tv / 25;
            float pos = pos_is_t ? (float)tt : (float)(tv - tt * 25);
            float ang = pos * dv;
            float pe = (c & 1) ? __cosf(ang) : __sinf(ang);
            int tl = col / 25, j = col - tl * 25;
            xs[(c * 4 + tl) * 28 + j] = vals[e] + pe;
        }
    }
    __syncthreads();
    const int r = threadIdx.x & 63, g = threadIdx.x >> 6;
    float a0[25], a1[25], a2[25];
#pragma unroll
    for (int j = 0; j < 25; j++) { a0[j] = 0.f; a1[j] = 0.f; a2[j] = 0.f; }
#pragma unroll 2
    for (int c = 0; c < 128; c++) {
        const float* yy = &xs[(c * 4 + g) * 28];
        const float* wc = WT + c * 192 + r;
        float w0 = wc[0], w1 = wc[64], w2 = wc[128];
        fma25(a0, w0, yy); fma25(a1, w1, yy); fma25(a2, w2, yy);
    }
    float b0 = bias[r], b1 = bias[r + 64], b2 = bias[r + 128];
    ushort* on = out + (size_t)n * 307200;
#pragma unroll
    for (int k = 0; k < 6; k++) {
        const int band = k >> 1, half = k & 1;
        __syncthreads();
        if ((r >> 5) == half) {
            int rr = r & 31;
#pragma unroll
            for (int j = 0; j < 25; j++) {
                float v = (band == 0) ? a0[j] + b0 : (band == 1) ? a1[j] + b1 : a2[j] + b2;
                buf[(rr * 4 + g) * 25 + j] = v;
            }
        }
        __syncthreads();
        const int rbase = band * 64 + half * 32;
        for (int i = threadIdx.x; i < 1600; i += 256) {
            int rr = i / 50, w = i - rr * 50, u = w * 2, t = u / 25, j = u - t * 25;
            float v0 = buf[(rr * 4 + t) * 25 + j];
            float v1 = (j == 24) ? buf[(rr * 4 + t + 1) * 25] : buf[(rr * 4 + t) * 25 + j + 1];
            uint p = (uint)f2bf(v0) | ((uint)f2bf(v1) << 16);
            *(uint*)(on + (size_t)(rbase + rr) * 1600 + tv0 + u) = p;
        }
    }
}

// ---- att_s (unchanged from passing round) ----
__global__ __launch_bounds__(128) void att_s_kernel(
    const ushort* __restrict__ qk, const float* __restrict__ alphas,
    const float* __restrict__ att0, float* __restrict__ attOut)
{
    __shared__ float sm[2 * 32 * 404];
    float* qs = sm;
    float* ks = sm + 32 * 404;
    const int s = blockIdx.x, n = blockIdx.y;
    const ushort* qkn = qk + (size_t)n * 307200;
    const int ut = threadIdx.x >> 3;
    const int rg = threadIdx.x & 7;
    const int u0 = ut * 2, u1 = u0 + 1;
    float acc0[25], acc1[25];
#pragma unroll
    for (int v = 0; v < 25; v++) { acc0[v] = 0.f; acc1[v] = 0.f; }
    for (int tc = 0; tc < 4; tc++) {
        __syncthreads();
        for (int i = threadIdx.x; i < 6400; i += 128) {
            int r = i / 200, col2 = i - r * 200;
            uint uq = *(const uint*)(qkn + (s * 32 + r) * 1600 + tc * 400 + col2 * 2);
            uint uk = *(const uint*)(qkn + (96 + s * 32 + r) * 1600 + tc * 400 + col2 * 2);
            qs[r * 404 + col2 * 2]     = __uint_as_float((uq & 0xffffu) << 16);
            qs[r * 404 + col2 * 2 + 1] = __uint_as_float(uq & 0xffff0000u);
            ks[r * 404 + col2 * 2]     = __uint_as_float((uk & 0xffffu) << 16);
            ks[r * 404 + col2 * 2 + 1] = __uint_as_float(uk & 0xffff0000u);
        }
        __syncthreads();
        if (ut < 13) {
            const int uu1 = (u1 < 25) ? u1 : 0;
#pragma unroll
            for (int rr = 0; rr < 4; rr++) {
                int r = rg * 4 + rr;
                for (int t = 0; t < 16; t++) {
                    float qa = qs[r * 404 + t * 25 + u0];
                    float qb = qs[r * 404 + t * 25 + uu1];
                    const float* kr = &ks[r * 404 + t * 25];
#pragma unroll
                    for (int v = 0; v < 25; v++) {
                        float kv = kr[v];
                        acc0[v] += qa * kv; acc1[v] += qb * kv;
                    }
                }
            }
        }
    }
    __syncthreads();
    float* red = sm;
    if (ut < 13) {
#pragma unroll
        for (int v = 0; v < 25; v++) red[rg * 650 + u0 * 25 + v] = acc0[v];
        if (u1 < 25) {
#pragma unroll
            for (int v = 0; v < 25; v++) red[rg * 650 + u1 * 25 + v] = acc1[v];
        }
    }
    __syncthreads();
    float alpha = alphas[s];
    for (int i = threadIdx.x; i < 625; i += 128) {
        float sum = 0.f;
#pragma unroll
        for (int g = 0; g < 8; g++) sum += red[g * 650 + i];
        attOut[(size_t)(n * 3 + s) * 625 + i] =
            tanhf(sum * (1.0f / 2048.0f)) * alpha + att0[s * 625 + i];
    }
}

// ---- att_t (unchanged from passing round) ----
__global__ __launch_bounds__(128) void att_t_kernel(
    const ushort* __restrict__ qk, const float* __restrict__ alphat,
    const float* __restrict__ att0, float* __restrict__ attOut)
{
    __shared__ float sm[2 * 13600];
    float* qst = sm;
    float* kst = sm + 13600;
    const int s = blockIdx.x, n = blockIdx.y;
    const ushort* qkn = qk + (size_t)n * 307200;
    const int tg = threadIdx.x & 15;
    const int qg = (threadIdx.x >> 4) & 3;
    const int rh = threadIdx.x >> 6;
    const int t0 = tg * 4, q0 = qg * 16;
    float acc[4][16];
#pragma unroll
    for (int i = 0; i < 4; i++)
#pragma unroll
        for (int jj = 0; jj < 16; jj++) acc[i][jj] = 0.f;
    for (int rc = 0; rc < 4; rc++) {
        __syncthreads();
        for (int i = threadIdx.x; i < 6400; i += 128) {
            int rr = i / 800; int rem2 = (i - rr * 800) * 2;
            uint uq = *(const uint*)(qkn + (s * 32 + rc * 8 + rr) * 1600 + rem2);
            uint uk = *(const uint*)(qkn + (96 + s * 32 + rc * 8 + rr) * 1600 + rem2);
            int ta = rem2 / 25, va = rem2 - ta * 25;
            int tb = (rem2 + 1) / 25, vb = (rem2 + 1) - tb * 25;
            qst[rr * 1700 + va * 68 + ta] = __uint_as_float((uq & 0xffffu) << 16);
            qst[rr * 1700 + vb * 68 + tb] = __uint_as_float(uq & 0xffff0000u);
            kst[rr * 1700 + va * 68 + ta] = __uint_as_float((uk & 0xffffu) << 16);
            kst[rr * 1700 + vb * 68 + tb] = __uint_as_float(uk & 0xffff0000u);
        }
        __syncthreads();
#pragma unroll
        for (int rr = 0; rr < 4; rr++) {
            int r = rh * 4 + rr;
            for (int v = 0; v < 25; v++) {
                float4 qv = *(const float4*)&qst[r * 1700 + v * 68 + t0];
                const float4* kp = (const float4*)&kst[r * 1700 + v * 68 + q0];
                float qa[4] = { qv.x, qv.y, qv.z, qv.w };
#pragma unroll
                for (int b = 0; b < 4; b++) {
                    float4 kv = kp[b];
#pragma unroll
                    for (int i = 0; i < 4; i++) {
                        acc[i][b * 4 + 0] += qa[i] * kv.x;
                        acc[i][b * 4 + 1] += qa[i] * kv.y;
                        acc[i][b * 4 + 2] += qa[i] * kv.z;
                        acc[i][b * 4 + 3] += qa[i] * kv.w;
                    }
                }
            }
        }
    }
    __syncthreads();
    float* red = sm;
#pragma unroll
    for (int i = 0; i < 4; i++)
#pragma unroll
        for (int jj = 0; jj < 16; jj++)
            red[rh * 4096 + (t0 + i) * 64 + q0 + jj] = acc[i][jj];
    __syncthreads();
    float alpha = alphat[s];
    for (int i = threadIdx.x; i < 4096; i += 128) {
        float sum = red[i] + red[4096 + i];
        attOut[(size_t)(n * 3 + s) * 4096 + i] =
            tanhf(sum * (1.0f / 800.0f)) * alpha + att0[s * 4096 + i];
    }
}

// ------- T1/S1: G[n'][s][t][v][128o] (bf16) = sum_c WT[s][c][o] * src[c][t*25+v] -------
__global__ __launch_bounds__(256) void t1_gemm(
    const float* __restrict__ src /*quarter base*/, const float* __restrict__ WT /*[3][128][128]*/,
    ushort* __restrict__ G)
{
    __shared__ float xs[128 * 4 * 28];
    const int np = blockIdx.y, tv0 = blockIdx.x * 100, t0 = blockIdx.x * 4;
    const float* sn = src + (size_t)np * 204800;
    for (int i = threadIdx.x; i < 3200; i += 256) {
        int c = i / 25, col4 = i - c * 25;
        float4 xv = *(const float4*)(sn + c * 1600 + tv0 + col4 * 4);
        float vals[4] = { xv.x, xv.y, xv.z, xv.w };
#pragma unroll
        for (int e = 0; e < 4; e++) {
            int col = col4 * 4 + e;
            int tl = col / 25, j = col - tl * 25;
            xs[(c * 4 + tl) * 28 + j] = vals[e];
        }
    }
    __syncthreads();
    const int o = threadIdx.x & 63, g = threadIdx.x >> 6;
    for (int s = 0; s < 3; s++) {
        float a0[25], a1[25];
#pragma unroll
        for (int j = 0; j < 25; j++) { a0[j] = 0.f; a1[j] = 0.f; }
        const float* Ws = WT + s * 16384;
#pragma unroll 2
        for (int c = 0; c < 128; c++) {
            const float* yy = &xs[(c * 4 + g) * 28];
            float w0 = Ws[c * 128 + o], w1 = Ws[c * 128 + o + 64];
            fma25(a0, w0, yy); fma25(a1, w1, yy);
        }
        ushort* Gr = G + ((size_t)(np * 3 + s) * 64 + t0 + g) * 3200;
#pragma unroll
        for (int j = 0; j < 25; j++) {
            Gr[j * 128 + o]      = f2bf(a0[j]);
            Gr[j * 128 + o + 64] = f2bf(a1[j]);
        }
    }
}

// ------- S2: y1[o,t,v] = lrelu(x + BN(sum_{s,u} attS[s,u,v] H[o,s,t,u])) (bf16 out) -------
__global__ __launch_bounds__(256) void s2_kernel(
    const ushort* __restrict__ H, const float* __restrict__ attS /*quarter base*/,
    const float* __restrict__ xres /*quarter base*/, const float* __restrict__ bnp,
    const float* __restrict__ bo, ushort* __restrict__ y1)
{
    __shared__ float aS[3 * 25 * 28];
    __shared__ ushort Hc[16 * 408];     // [t][u][16o] padded (stride 408 u16)
    __shared__ float xst[16 * 400];     // [o][16t*25]
    const int np = blockIdx.y, o0 = blockIdx.x * 16;
    const int o = threadIdx.x >> 4, tl = threadIdx.x & 15;
    const int o_act = o0 + o;
    float scale = bnp[o_act] * rsqrtf(bnp[384 + o_act] + 1e-5f);
    float off = (bo[o_act] - bnp[256 + o_act]) * scale + bnp[128 + o_act];
    for (int i = threadIdx.x; i < 1875; i += 256) {
        int s = i / 625, rem = i - s * 625, u = rem / 25, v = rem - u * 25;
        aS[(s * 25 + u) * 28 + v] = attS[(size_t)np * 1875 + i];
    }
    for (int tc = 0; tc < 4; tc++) {
        __syncthreads();
        for (int i = threadIdx.x; i < 1600; i += 256) {
            int oi = i / 100, w4 = i - oi * 100;
            *(float4*)&xst[oi * 400 + w4 * 4] =
                *(const float4*)(xres + (size_t)np * 204800 + (size_t)(o0 + oi) * 1600 + tc * 400 + w4 * 4);
        }
        float acc[25];
#pragma unroll
        for (int v = 0; v < 25; v++) acc[v] = 0.f;
        for (int s = 0; s < 3; s++) {
            __syncthreads();
            for (int i = threadIdx.x; i < 3200; i += 256) {
                int t = i / 200, rem = i - t * 200, v = rem / 8, w = rem - v * 8;
                uint val = *(const uint*)(H + ((size_t)(np * 3 + s) * 64 + tc * 16 + t) * 3200 + v * 128 + o0 + w * 2);
                ((uint*)Hc)[t * 204 + v * 8 + w] = val;
            }
            __syncthreads();
            float h[25];
#pragma unroll
            for (int u = 0; u < 25; u++)
                h[u] = __uint_as_float(((uint)Hc[tl * 408 + u * 16 + o]) << 16);
            const float* as = &aS[s * 25 * 28];
#pragma unroll
            for (int u = 0; u < 25; u++) fma25(acc, h[u], as + u * 28);
        }
        __syncthreads();
#pragma unroll
        for (int v = 0; v < 25; v++) {
            float rr = xst[o * 400 + tl * 25 + v] + (acc[v] * scale + off);
            rr = rr > 0.f ? rr : 0.1f * rr;
            xst[o * 400 + tl * 25 + v] = rr;
        }
        __syncthreads();
        for (int i = threadIdx.x; i < 3200; i += 256) {
            int oi = i / 200, w = i - oi * 200, u = w * 2;
            uint p = (uint)f2bf(xst[oi * 400 + u]) | ((uint)f2bf(xst[oi * 400 + u + 1]) << 16);
            *(uint*)(y1 + (size_t)np * 204800 + (size_t)(o0 + oi) * 1600 + tc * 400 + u) = p;
        }
    }
}

// ------- T2: z9[o,q,v] = lrelu(y + BN(sum_{s,t} attT[s,t,q] G[o,s,t,v])) (bf16 out) -------
__global__ __launch_bounds__(256) void t2_kernel(
    const ushort* __restrict__ G, const float* __restrict__ attT /*quarter base*/,
    const float* __restrict__ yres /*quarter base*/, const float* __restrict__ bnp,
    const float* __restrict__ bo, ushort* __restrict__ z9)
{
    __shared__ float aT[16 * 64];
    __shared__ ushort Gc[16 * 408];
    __shared__ float yt[16 * 400];
    const int np = blockIdx.y, o0 = blockIdx.x * 16;
    const int o = threadIdx.x >> 4, qh = threadIdx.x & 15;
    const int o_act = o0 + o;
    float scale = bnp[o_act] * rsqrtf(bnp[384 + o_act] + 1e-5f);
    float off = (bo[o_act] - bnp[256 + o_act]) * scale + bnp[128 + o_act];
    float acc[4][25];
#pragma unroll
    for (int i = 0; i < 4; i++)
#pragma unroll
        for (int v = 0; v < 25; v++) acc[i][v] = 0.f;
    for (int s = 0; s < 3; s++) {
        for (int tc = 0; tc < 4; tc++) {
            __syncthreads();
            for (int i = threadIdx.x; i < 1024; i += 256)
                aT[i] = attT[(size_t)np * 12288 + s * 4096 + tc * 1024 + i];
            for (int i = threadIdx.x; i < 3200; i += 256) {
                int t = i / 200, rem = i - t * 200, v = rem / 8, w = rem - v * 8;
                uint val = *(const uint*)(G + ((size_t)(np * 3 + s) * 64 + tc * 16 + t) * 3200 + v * 128 + o0 + w * 2);
                ((uint*)Gc)[t * 204 + v * 8 + w] = val;
            }
            __syncthreads();
            for (int tt = 0; tt < 16; tt++) {
                float gv[25];
#pragma unroll
                for (int v = 0; v < 25; v++)
                    gv[v] = __uint_as_float(((uint)Gc[tt * 408 + v * 16 + o]) << 16);
#pragma unroll
                for (int i = 0; i < 4; i++) {
                    float a = aT[tt * 64 + qh + i * 16];
                    fma25r(acc[i], a, gv);
                }
            }
        }
    }
#pragma unroll
    for (int i = 0; i < 4; i++) {
        __syncthreads();
        for (int k = threadIdx.x; k < 1600; k += 256) {
            int oi = k / 100, w4 = k - oi * 100;
            *(float4*)&yt[oi * 400 + w4 * 4] =
                *(const float4*)(yres + (size_t)np * 204800 + (size_t)(o0 + oi) * 1600 + i * 400 + w4 * 4);
        }
        __syncthreads();
#pragma unroll
        for (int v = 0; v < 25; v++) {
            float rr = yt[o * 400 + qh * 25 + v] + (acc[i][v] * scale + off);
            rr = rr > 0.f ? rr : 0.1f * rr;
            yt[o * 400 + qh * 25 + v] = rr;
        }
        __syncthreads();
        for (int k = threadIdx.x; k < 3200; k += 256) {
            int oi = k / 200, w = k - oi * 200, u = w * 2;
            uint p = (uint)f2bf(yt[oi * 400 + u]) | ((uint)f2bf(yt[oi * 400 + u + 1]) << 16);
            *(uint*)(z9 + (size_t)np * 204800 + (size_t)(o0 + oi) * 1600 + i * 400 + u) = p;
        }
    }
}

// ------- cbr: out = lrelu(res + BN(WT^T @ in + b)); res/out may alias -------
__global__ __launch_bounds__(256) void cbr_v2(
    const ushort* __restrict__ in /*quarter base bf16*/, const float* res /*quarter base*/,
    const float* __restrict__ WT /*[128c][128o]*/, const float* __restrict__ bias,
    const float* __restrict__ bnp, float* outp /*quarter base*/)
{
    __shared__ float ins[128 * 80];
    __shared__ float sc_l[128], of_l[128];
    const int np = blockIdx.y, tv0 = blockIdx.x * 80;
    if (threadIdx.x < 128) {
        int oo = threadIdx.x;
        float sc = bnp[oo] * rsqrtf(bnp[384 + oo] + 1e-5f);
        sc_l[oo] = sc;
        of_l[oo] = (bias[oo] - bnp[256 + oo]) * sc + bnp[128 + oo];
    }
    for (int i = threadIdx.x; i < 5120; i += 256) {
        int c = i / 40, w = i - c * 40;
        uint u = *(const uint*)(in + (size_t)np * 204800 + c * 1600 + tv0 + w * 2);
        ins[c * 80 + w * 2]     = __uint_as_float((u & 0xffffu) << 16);
        ins[c * 80 + w * 2 + 1] = __uint_as_float(u & 0xffff0000u);
    }
    __syncthreads();
    const int o = threadIdx.x & 63, cg = threadIdx.x >> 6;
    float acc0[20], acc1[20];
#pragma unroll
    for (int j = 0; j < 20; j++) { acc0[j] = 0.f; acc1[j] = 0.f; }
#pragma unroll 2
    for (int c = 0; c < 128; c++) {
        float w0 = WT[c * 128 + o], w1 = WT[c * 128 + o + 64];
        const float* yy = &ins[c * 80 + cg * 20];
#pragma unroll
        for (int jb = 0; jb < 5; jb++) {
            float4 q = *(const float4*)(yy + jb * 4);
            acc0[jb*4+0] += w0 * q.x; acc0[jb*4+1] += w0 * q.y;
            acc0[jb*4+2] += w0 * q.z; acc0[jb*4+3] += w0 * q.w;
            acc1[jb*4+0] += w1 * q.x; acc1[jb*4+1] += w1 * q.y;
            acc1[jb*4+2] += w1 * q.z; acc1[jb*4+3] += w1 * q.w;
        }
    }
    __syncthreads();
#pragma unroll
    for (int j = 0; j < 20; j++) {
        ins[o * 80 + cg * 20 + j] = acc0[j];
        ins[(o + 64) * 80 + cg * 20 + j] = acc1[j];
    }
    __syncthreads();
    for (int k = threadIdx.x; k < 2560; k += 256) {
        int row = k / 20, col4 = k - row * 20;
        size_t gofs = (size_t)np * 204800 + (size_t)row * 1600 + tv0 + col4 * 4;
        float4 rv = *(const float4*)(res + gofs);
        float sc = sc_l[row], of = of_l[row];
        float h0 = ins[row * 80 + col4 * 4 + 0] * sc + of + rv.x;
        float h1 = ins[row * 80 + col4 * 4 + 1] * sc + of + rv.y;
        float h2 = ins[row * 80 + col4 * 4 + 2] * sc + of + rv.z;
        float h3 = ins[row * 80 + col4 * 4 + 3] * sc + of + rv.w;
        float4 ov;
        ov.x = h0 > 0.f ? h0 : 0.1f * h0;
        ov.y = h1 > 0.f ? h1 : 0.1f * h1;
        ov.z = h2 > 0.f ? h2 : 0.1f * h2;
        ov.w = h3 > 0.f ? h3 : 0.1f * h3;
        *(float4*)(outp + gofs) = ov;
    }
}

extern "C" void kernel_launch(void* const* d_in, const int* in_sizes, int n_in,
                              void* d_out, int out_size, void* d_ws, size_t ws_size,
                              hipStream_t stream)
{
    (void)in_sizes; (void)n_in; (void)out_size; (void)ws_size;
    const float* x      = (const float*)d_in[0];
    const float* Wqk_s  = (const float*)d_in[1];
    const float* bqk_s  = (const float*)d_in[2];
    const float* alphas = (const float*)d_in[3];
    const float* att0s  = (const float*)d_in[4];
    const float* Wo_s   = (const float*)d_in[5];
    const float* bo_s   = (const float*)d_in[6];
    const float* bn_o_s = (const float*)d_in[7];
    const float* Wf_s   = (const float*)d_in[8];
    const float* bf_s   = (const float*)d_in[9];
    const float* bn_f_s = (const float*)d_in[10];
    const float* Wqk_t  = (const float*)d_in[11];
    const float* bqk_t  = (const float*)d_in[12];
    const float* alphat = (const float*)d_in[13];
    const float* att0t  = (const float*)d_in[14];
    const float* Wo_t   = (const float*)d_in[15];
    const float* bo_t   = (const float*)d_in[16];
    const float* bn_o_t = (const float*)d_in[17];
    const float* Wf_t   = (const float*)d_in[18];
    const float* bf_t   = (const float*)d_in[19];
    const float* bn_f_t = (const float*)d_in[20];

    float* out = (float*)d_out;
    const size_t CTV = 204800;
    // ws layout (bytes):
    //  [0, 78,643,200)  qk bf16 (full) — later reused as: A=[0,39,321,600) G/H quarter bf16,
    //                                                      B=[39,321,600, 52,428,800) y1/z9 quarter bf16
    //  [78,643,200, 79,603,200)  attS fp32
    //  [79,603,200, 85,894,656)  attT fp32
    //  [85,894,656, 86,615,552)  WT (transposed weights, fp32)
    ushort* qk   = (ushort*)d_ws;
    ushort* Gbuf = (ushort*)d_ws;
    ushort* y1q  = (ushort*)((char*)d_ws + 39321600);
    float*  attS = (float*)((char*)d_ws + 78643200);
    float*  attT = (float*)((char*)d_ws + 79603200);
    float*  WTb  = (float*)((char*)d_ws + 85894656);
    float* WToS  = WTb;
    float* WTfS  = WTb + 49152;
    float* WToT  = WTb + 65536;
    float* WTfT  = WTb + 114688;
    float* WTqkS = WTb + 131072;
    float* WTqkT = WTb + 155648;

    wt_prep<<<704, 256, 0, stream>>>(Wo_s, Wf_s, Wo_t, Wf_t, Wqk_s, Wqk_t, WTb);

    dim3 gqk(16, 128), gatt(3, 128), gt1(16, 32), gs2(8, 32), gcbr(20, 32);

    // ---- spatial ----
    qk_pe_v2<<<gqk, 256, 0, stream>>>(x, WTqkS, bqk_s, qk, 0);
    att_s_kernel<<<gatt, 128, 0, stream>>>(qk, alphas, att0s, attS);
    for (int h = 0; h < 4; h++) {
        size_t n0 = (size_t)h * 32;
        t1_gemm<<<gt1, 256, 0, stream>>>(x + n0 * CTV, WToS, Gbuf);
        s2_kernel<<<gs2, 256, 0, stream>>>(Gbuf, attS + n0 * 1875, x + n0 * CTV,
                                           bn_o_s, bo_s, y1q);
        cbr_v2<<<gcbr, 256, 0, stream>>>(y1q, x + n0 * CTV, WTfS, bf_s, bn_f_s,
                                         out + n0 * CTV);
    }

    // ---- temporal ----
    qk_pe_v2<<<gqk, 256, 0, stream>>>(out, WTqkT, bqk_t, qk, 1);
    att_t_kernel<<<gatt, 128, 0, stream>>>(qk, alphat, att0t, attT);
    for (int h = 0; h < 4; h++) {
        size_t n0 = (size_t)h * 32;
        t1_gemm<<<gt1, 256, 0, stream>>>(out + n0 * CTV, WToT, Gbuf);
        t2_kernel<<<gs2, 256, 0, stream>>>(Gbuf, attT + n0 * 12288, out + n0 * CTV,
                                           bn_o_t, bo_t, y1q);
        cbr_v2<<<gcbr, 256, 0, stream>>>(y1q, out + n0 * CTV, WTfT, bf_t, bn_f_t,
                                         out + n0 * CTV);
    }
}

// Round 4
// 2022.542 us; speedup vs baseline: 1.8797x; 1.4136x over previous
//
#include <hip/hip_runtime.h>
#include <math.h>

// Dims: N=128, C=128, T=64, V=25, S=3, R=32; TV=1600, CTV=204800.
// spatial: y1 = lrelu(x + BN(sum_{s,u} attS[s,u,v] * H[o,s,t,u])), H = Wo_s x  (t1_mfma)
// temporal: z9 = lrelu(y + BN(sum_{s,t} attT[s,t,q] * G[o,s,t,v])), G = Wo_t y (t1_mfma)
// G/H bf16 [np][s][t][v][128o]. 4 quarters of 32 n.
// att_s/att_t: K-split partial sums via atomicAdd + finalize (tanh*alpha+att0).

typedef __attribute__((ext_vector_type(8))) short short8v;
typedef __attribute__((ext_vector_type(4))) float f32x4;

__device__ __forceinline__ ushort f2bf(float f) {
    uint b = __float_as_uint(f);
    uint r = b + 0x7fffu + ((b >> 16) & 1u);
    return (ushort)(r >> 16);
}
__device__ __forceinline__ float bf2f(ushort h) {
    return __uint_as_float(((uint)h) << 16);
}

__device__ __forceinline__ void fma25(float (&acc)[25], float w, const float* yy) {
#pragma unroll
    for (int jb = 0; jb < 6; jb++) {
        float4 q = *(const float4*)(yy + jb * 4);
        acc[jb*4+0] += w * q.x; acc[jb*4+1] += w * q.y;
        acc[jb*4+2] += w * q.z; acc[jb*4+3] += w * q.w;
    }
    acc[24] += w * yy[24];
}

__device__ __forceinline__ void fma25r(float* acc, float a, const float* g) {
#pragma unroll
    for (int v = 0; v < 25; v++) acc[v] += a * g[v];
}

// ---------------- weight prep (tiny, once per call) ----------------
// WTb float slots: [0,49152) WToS_bf (as ushort, [3][128o][128c])
//                  [49152,65536) WTfS fp32 [c][o]
//                  [65536,114688) WToT_bf (as ushort, [3][128o][128c])
//                  [114688,131072) WTfT fp32 [c][o]
//                  [131072,155648) WTqkS fp32 [c][192r]
//                  [155648,180224) WTqkT fp32 [c][192r]
__global__ __launch_bounds__(256) void wt_prep(
    const float* __restrict__ Wo_s, const float* __restrict__ Wf_s,
    const float* __restrict__ Wo_t, const float* __restrict__ Wf_t,
    const float* __restrict__ Wqk_s, const float* __restrict__ Wqk_t,
    float* __restrict__ WT)
{
    int idx = blockIdx.x * 256 + threadIdx.x;
    if (idx >= 180224) return;
    if (idx < 49152) {                       // WToS_bf[s][o][c] (ushort)
        int s = idx / 16384, rem = idx % 16384, o = rem / 128, c = rem % 128;
        ((ushort*)WT)[idx] = f2bf(Wo_s[o * 384 + s * 128 + c]);
    } else if (idx < 65536) {                // WTfS[c][o]
        int i = idx - 49152, c = i / 128, o = i % 128;
        WT[idx] = Wf_s[o * 128 + c];
    } else if (idx < 114688) {               // WToT_bf[s][o][c] (ushort)
        int i = idx - 65536, s = i / 16384, rem = i % 16384, o = rem / 128, c = rem % 128;
        ((ushort*)(WT + 65536))[i] = f2bf(Wo_t[o * 384 + s * 128 + c]);
    } else if (idx < 131072) {               // WTfT[c][o]
        int i = idx - 114688, c = i / 128, o = i % 128;
        WT[idx] = Wf_t[o * 128 + c];
    } else if (idx < 155648) {               // WTqkS[c][r]
        int i = idx - 131072, c = i / 192, r = i % 192;
        WT[idx] = Wqk_s[r * 128 + c];
    } else {                                 // WTqkT[c][r]
        int i = idx - 155648, c = i / 192, r = i % 192;
        WT[idx] = Wqk_t[r * 128 + c];
    }
}

// ---------------- qk = Wqk @ (x + PE), bf16 out [n][192][1600] ----------------
__global__ __launch_bounds__(256) void qk_pe_v2(
    const float* __restrict__ src, const float* __restrict__ WT, // [128c][192r]
    const float* __restrict__ bias, ushort* __restrict__ out, int pos_is_t)
{
    __shared__ float xs[128 * 4 * 28];   // [c][t_local][25 (+3 pad)]
    __shared__ float buf[32 * 4 * 25];   // store-exchange
    const int n = blockIdx.y, tv0 = blockIdx.x * 100;
    const float* sn = src + (size_t)n * 204800;
    for (int i = threadIdx.x; i < 3200; i += 256) {
        int c = i / 25, col4 = i - c * 25;
        float4 xv = *(const float4*)(sn + c * 1600 + tv0 + col4 * 4);
        float dv = __expf(-0.14391156831212787f * (float)(c >> 1)); // ln(1e4)/64
        float vals[4] = { xv.x, xv.y, xv.z, xv.w };
#pragma unroll
        for (int e = 0; e < 4; e++) {
            int col = col4 * 4 + e;
            int tv = tv0 + col;
            int tt = tv / 25;
            float pos = pos_is_t ? (float)tt : (float)(tv - tt * 25);
            float ang = pos * dv;
            float pe = (c & 1) ? __cosf(ang) : __sinf(ang);
            int tl = col / 25, j = col - tl * 25;
            xs[(c * 4 + tl) * 28 + j] = vals[e] + pe;
        }
    }
    __syncthreads();
    const int r = threadIdx.x & 63, g = threadIdx.x >> 6;
    float a0[25], a1[25], a2[25];
#pragma unroll
    for (int j = 0; j < 25; j++) { a0[j] = 0.f; a1[j] = 0.f; a2[j] = 0.f; }
#pragma unroll 2
    for (int c = 0; c < 128; c++) {
        const float* yy = &xs[(c * 4 + g) * 28];
        const float* wc = WT + c * 192 + r;
        float w0 = wc[0], w1 = wc[64], w2 = wc[128];
        fma25(a0, w0, yy); fma25(a1, w1, yy); fma25(a2, w2, yy);
    }
    float b0 = bias[r], b1 = bias[r + 64], b2 = bias[r + 128];
    ushort* on = out + (size_t)n * 307200;
#pragma unroll
    for (int k = 0; k < 6; k++) {
        const int band = k >> 1, half = k & 1;
        __syncthreads();
        if ((r >> 5) == half) {
            int rr = r & 31;
#pragma unroll
            for (int j = 0; j < 25; j++) {
                float v = (band == 0) ? a0[j] + b0 : (band == 1) ? a1[j] + b1 : a2[j] + b2;
                buf[(rr * 4 + g) * 25 + j] = v;
            }
        }
        __syncthreads();
        const int rbase = band * 64 + half * 32;
        for (int i = threadIdx.x; i < 1600; i += 256) {
            int rr = i / 50, w = i - rr * 50, u = w * 2, t = u / 25, j = u - t * 25;
            float v0 = buf[(rr * 4 + t) * 25 + j];
            float v1 = (j == 24) ? buf[(rr * 4 + t + 1) * 25] : buf[(rr * 4 + t) * 25 + j + 1];
            uint p = (uint)f2bf(v0) | ((uint)f2bf(v1) << 16);
            *(uint*)(on + (size_t)(rbase + rr) * 1600 + tv0 + u) = p;
        }
    }
}

// ---------------- att_s partial: sum[u,v] += sum_{chunk p} Q[p,u]K[p,v] ----------------
__global__ __launch_bounds__(128) void att_s_partial(
    const ushort* __restrict__ qk, float* __restrict__ sum)
{
    __shared__ float qs[25 * 260];
    __shared__ float ks[25 * 260];
    const int s = blockIdx.x >> 3, rc = blockIdx.x & 7, n = blockIdx.y;
    const ushort* qb = qk + (size_t)n * 307200 + (size_t)(s * 32 + rc * 4) * 1600;
    const ushort* kb = qb + 96 * 1600;
    for (int i = threadIdx.x; i < 6400; i += 128) {
        int rl = i / 1600, rem = i - rl * 1600, t = rem / 25, u = rem - t * 25;
        int a = u * 260 + rl * 64 + t;
        qs[a] = bf2f(qb[i]);
        ks[a] = bf2f(kb[i]);
    }
    __syncthreads();
    if (threadIdx.x < 125) {
        const int u = threadIdx.x / 5, vg = threadIdx.x % 5;
        float acc[5] = {0.f, 0.f, 0.f, 0.f, 0.f};
        for (int p4 = 0; p4 < 64; p4++) {
            float4 qv = *(const float4*)&qs[u * 260 + p4 * 4];
#pragma unroll
            for (int j = 0; j < 5; j++) {
                float4 kv = *(const float4*)&ks[(vg * 5 + j) * 260 + p4 * 4];
                acc[j] += qv.x * kv.x + qv.y * kv.y + qv.z * kv.z + qv.w * kv.w;
            }
        }
        float* dst = sum + (size_t)(n * 3 + s) * 625 + u * 25 + vg * 5;
#pragma unroll
        for (int j = 0; j < 5; j++) atomicAdd(dst + j, acc[j]);
    }
}

__global__ __launch_bounds__(256) void att_s_final(
    float* __restrict__ att, const float* __restrict__ alphas,
    const float* __restrict__ att0)
{
    int idx = blockIdx.x * 256 + threadIdx.x;
    if (idx >= 240000) return;
    int rem = idx % 1875, s = rem / 625, uv = rem - s * 625;
    att[idx] = tanhf(att[idx] * (1.0f / 2048.0f)) * alphas[s] + att0[s * 625 + uv];
}

// ---------------- att_t partial: sum[t,q] += sum_{chunk r,v} Q[r,t,v]K[r,q,v] ----------------
__global__ __launch_bounds__(256) void att_t_partial(
    const ushort* __restrict__ qk, float* __restrict__ sum)
{
    __shared__ float qs[100 * 68];
    __shared__ float ks[100 * 68];
    const int s = blockIdx.x >> 3, rc = blockIdx.x & 7, n = blockIdx.y;
    const ushort* qb = qk + (size_t)n * 307200 + (size_t)(s * 32 + rc * 4) * 1600;
    const ushort* kb = qb + 96 * 1600;
    for (int i = threadIdx.x; i < 6400; i += 256) {
        int rl = i / 1600, rem = i - rl * 1600, t = rem / 25, v = rem - t * 25;
        int a = (rl * 25 + v) * 68 + t;
        qs[a] = bf2f(qb[i]);
        ks[a] = bf2f(kb[i]);
    }
    __syncthreads();
    const int t0 = (threadIdx.x >> 4) * 4, q0 = (threadIdx.x & 15) * 4;
    float acc[4][4];
#pragma unroll
    for (int i = 0; i < 4; i++)
#pragma unroll
        for (int j = 0; j < 4; j++) acc[i][j] = 0.f;
    for (int rv = 0; rv < 100; rv++) {
        float4 qv = *(const float4*)&qs[rv * 68 + t0];
        float4 kv = *(const float4*)&ks[rv * 68 + q0];
        float qa[4] = { qv.x, qv.y, qv.z, qv.w };
        float ka[4] = { kv.x, kv.y, kv.z, kv.w };
#pragma unroll
        for (int i = 0; i < 4; i++)
#pragma unroll
            for (int j = 0; j < 4; j++) acc[i][j] += qa[i] * ka[j];
    }
    float* dst = sum + (size_t)(n * 3 + s) * 4096;
#pragma unroll
    for (int i = 0; i < 4; i++)
#pragma unroll
        for (int j = 0; j < 4; j++)
            atomicAdd(dst + (t0 + i) * 64 + q0 + j, acc[i][j]);
}

__global__ __launch_bounds__(256) void att_t_final(
    float* __restrict__ att, const float* __restrict__ alphat,
    const float* __restrict__ att0)
{
    int idx = blockIdx.x * 256 + threadIdx.x;
    if (idx >= 1572864) return;
    int rem = idx % 12288, s = rem / 4096, tq = rem - s * 4096;
    att[idx] = tanhf(att[idx] * (1.0f / 800.0f)) * alphat[s] + att0[s * 4096 + tq];
}

// ------- t1 (MFMA): G[np][s][t][v][128o] bf16 = sum_c Wbf[s][o][c] * src[c][tv] -------
// D[m=tv][n=o] per (np,s): A[tv][c] = src^T (LDS xT), B[c][o] = Wbf (LDS Ws).
__global__ __launch_bounds__(256) void t1_mfma(
    const float* __restrict__ src /*quarter base*/,
    const ushort* __restrict__ Wbf /*[3][128o][128c] bf16*/,
    ushort* __restrict__ G)
{
    __shared__ ushort xT[160 * 136];  // [tv_local][c], stride 136 (pad 8)
    __shared__ ushort Ws[128 * 136];  // [o][c], stride 136
    const int np = blockIdx.y, tvb = blockIdx.x * 160;
    const float* sn = src + (size_t)np * 204800;
    // stage xT (transpose, pack c-pairs)
    for (int i = threadIdx.x; i < 2560; i += 256) {
        int tv4 = i % 40, cp = i / 40;
        float4 a = *(const float4*)(sn + (2 * cp) * 1600 + tvb + tv4 * 4);
        float4 b = *(const float4*)(sn + (2 * cp + 1) * 1600 + tvb + tv4 * 4);
        float av[4] = { a.x, a.y, a.z, a.w };
        float bv[4] = { b.x, b.y, b.z, b.w };
#pragma unroll
        for (int e = 0; e < 4; e++) {
            uint p = (uint)f2bf(av[e]) | ((uint)f2bf(bv[e]) << 16);
            ((uint*)xT)[(tv4 * 4 + e) * 68 + cp] = p;
        }
    }
    __syncthreads();
    const int lane = threadIdx.x & 63, wave = threadIdx.x >> 6;
    const int l15 = lane & 15, kg = lane >> 4;
    const int o_base = wave * 32;
    for (int s = 0; s < 3; s++) {
        // stage Ws
        for (int i = threadIdx.x; i < 2048; i += 256) {
            int o = i >> 4, seg = i & 15;
            uint4 wv = *(const uint4*)(Wbf + s * 16384 + o * 128 + seg * 8);
            *(uint4*)&Ws[o * 136 + seg * 8] = wv;
        }
        __syncthreads();
        short8v bfr[2][4];
#pragma unroll
        for (int nt = 0; nt < 2; nt++)
#pragma unroll
            for (int k = 0; k < 4; k++)
                bfr[nt][k] = *(short8v*)&Ws[(o_base + nt * 16 + l15) * 136 + k * 32 + kg * 8];
        ushort* Gs = G + (size_t)(np * 3 + s) * 64 * 3200;
        for (int mt = 0; mt < 10; mt++) {
            short8v af[4];
#pragma unroll
            for (int k = 0; k < 4; k++)
                af[k] = *(short8v*)&xT[(mt * 16 + l15) * 136 + k * 32 + kg * 8];
            f32x4 acc0 = {0.f, 0.f, 0.f, 0.f};
            f32x4 acc1 = {0.f, 0.f, 0.f, 0.f};
#pragma unroll
            for (int k = 0; k < 4; k++) {
                acc0 = __builtin_amdgcn_mfma_f32_16x16x32_bf16(af[k], bfr[0][k], acc0, 0, 0, 0);
                acc1 = __builtin_amdgcn_mfma_f32_16x16x32_bf16(af[k], bfr[1][k], acc1, 0, 0, 0);
            }
#pragma unroll
            for (int r = 0; r < 4; r++) {
                int tvg = tvb + mt * 16 + kg * 4 + r;
                int t = tvg / 25, v = tvg - t * 25;
                Gs[t * 3200 + v * 128 + o_base + l15]      = f2bf(acc0[r]);
                Gs[t * 3200 + v * 128 + o_base + 16 + l15] = f2bf(acc1[r]);
            }
        }
        __syncthreads();
    }
}

// ------- S2: y1[o,t,v] = lrelu(x + BN(sum_{s,u} attS[s,u,v] H[o,s,t,u])) (bf16 out) -------
__global__ __launch_bounds__(256) void s2_kernel(
    const ushort* __restrict__ H, const float* __restrict__ attS /*quarter base*/,
    const float* __restrict__ xres /*quarter base*/, const float* __restrict__ bnp,
    const float* __restrict__ bo, ushort* __restrict__ y1)
{
    __shared__ float aS[3 * 25 * 28];
    __shared__ ushort Hc[16 * 408];     // [t][u][16o] padded (stride 408 u16)
    __shared__ float xst[16 * 400];     // [o][16t*25]
    const int np = blockIdx.y, o0 = blockIdx.x * 16;
    const int o = threadIdx.x >> 4, tl = threadIdx.x & 15;
    const int o_act = o0 + o;
    float scale = bnp[o_act] * rsqrtf(bnp[384 + o_act] + 1e-5f);
    float off = (bo[o_act] - bnp[256 + o_act]) * scale + bnp[128 + o_act];
    for (int i = threadIdx.x; i < 1875; i += 256) {
        int s = i / 625, rem = i - s * 625, u = rem / 25, v = rem - u * 25;
        aS[(s * 25 + u) * 28 + v] = attS[(size_t)np * 1875 + i];
    }
    for (int tc = 0; tc < 4; tc++) {
        __syncthreads();
        for (int i = threadIdx.x; i < 1600; i += 256) {
            int oi = i / 100, w4 = i - oi * 100;
            *(float4*)&xst[oi * 400 + w4 * 4] =
                *(const float4*)(xres + (size_t)np * 204800 + (size_t)(o0 + oi) * 1600 + tc * 400 + w4 * 4);
        }
        float acc[25];
#pragma unroll
        for (int v = 0; v < 25; v++) acc[v] = 0.f;
        for (int s = 0; s < 3; s++) {
            __syncthreads();
            for (int i = threadIdx.x; i < 3200; i += 256) {
                int t = i / 200, rem = i - t * 200, v = rem / 8, w = rem - v * 8;
                uint val = *(const uint*)(H + ((size_t)(np * 3 + s) * 64 + tc * 16 + t) * 3200 + v * 128 + o0 + w * 2);
                ((uint*)Hc)[t * 204 + v * 8 + w] = val;
            }
            __syncthreads();
            float h[25];
#pragma unroll
            for (int u = 0; u < 25; u++)
                h[u] = __uint_as_float(((uint)Hc[tl * 408 + u * 16 + o]) << 16);
            const float* as = &aS[s * 25 * 28];
#pragma unroll
            for (int u = 0; u < 25; u++) fma25(acc, h[u], as + u * 28);
        }
        __syncthreads();
#pragma unroll
        for (int v = 0; v < 25; v++) {
            float rr = xst[o * 400 + tl * 25 + v] + (acc[v] * scale + off);
            rr = rr > 0.f ? rr : 0.1f * rr;
            xst[o * 400 + tl * 25 + v] = rr;
        }
        __syncthreads();
        for (int i = threadIdx.x; i < 3200; i += 256) {
            int oi = i / 200, w = i - oi * 200, u = w * 2;
            uint p = (uint)f2bf(xst[oi * 400 + u]) | ((uint)f2bf(xst[oi * 400 + u + 1]) << 16);
            *(uint*)(y1 + (size_t)np * 204800 + (size_t)(o0 + oi) * 1600 + tc * 400 + u) = p;
        }
    }
}

// ------- T2: z9[o,q,v] = lrelu(y + BN(sum_{s,t} attT[s,t,q] G[o,s,t,v])) (bf16 out) -------
__global__ __launch_bounds__(256) void t2_kernel(
    const ushort* __restrict__ G, const float* __restrict__ attT /*quarter base*/,
    const float* __restrict__ yres /*quarter base*/, const float* __restrict__ bnp,
    const float* __restrict__ bo, ushort* __restrict__ z9)
{
    __shared__ float aT[16 * 64];
    __shared__ ushort Gc[16 * 408];
    __shared__ float yt[16 * 400];
    const int np = blockIdx.y, o0 = blockIdx.x * 16;
    const int o = threadIdx.x >> 4, qh = threadIdx.x & 15;
    const int o_act = o0 + o;
    float scale = bnp[o_act] * rsqrtf(bnp[384 + o_act] + 1e-5f);
    float off = (bo[o_act] - bnp[256 + o_act]) * scale + bnp[128 + o_act];
    float acc[4][25];
#pragma unroll
    for (int i = 0; i < 4; i++)
#pragma unroll
        for (int v = 0; v < 25; v++) acc[i][v] = 0.f;
    for (int s = 0; s < 3; s++) {
        for (int tc = 0; tc < 4; tc++) {
            __syncthreads();
            for (int i = threadIdx.x; i < 1024; i += 256)
                aT[i] = attT[(size_t)np * 12288 + s * 4096 + tc * 1024 + i];
            for (int i = threadIdx.x; i < 3200; i += 256) {
                int t = i / 200, rem = i - t * 200, v = rem / 8, w = rem - v * 8;
                uint val = *(const uint*)(G + ((size_t)(np * 3 + s) * 64 + tc * 16 + t) * 3200 + v * 128 + o0 + w * 2);
                ((uint*)Gc)[t * 204 + v * 8 + w] = val;
            }
            __syncthreads();
            for (int tt = 0; tt < 16; tt++) {
                float gv[25];
#pragma unroll
                for (int v = 0; v < 25; v++)
                    gv[v] = __uint_as_float(((uint)Gc[tt * 408 + v * 16 + o]) << 16);
#pragma unroll
                for (int i = 0; i < 4; i++) {
                    float a = aT[tt * 64 + qh + i * 16];
                    fma25r(acc[i], a, gv);
                }
            }
        }
    }
#pragma unroll
    for (int i = 0; i < 4; i++) {
        __syncthreads();
        for (int k = threadIdx.x; k < 1600; k += 256) {
            int oi = k / 100, w4 = k - oi * 100;
            *(float4*)&yt[oi * 400 + w4 * 4] =
                *(const float4*)(yres + (size_t)np * 204800 + (size_t)(o0 + oi) * 1600 + i * 400 + w4 * 4);
        }
        __syncthreads();
#pragma unroll
        for (int v = 0; v < 25; v++) {
            float rr = yt[o * 400 + qh * 25 + v] + (acc[i][v] * scale + off);
            rr = rr > 0.f ? rr : 0.1f * rr;
            yt[o * 400 + qh * 25 + v] = rr;
        }
        __syncthreads();
        for (int k = threadIdx.x; k < 3200; k += 256) {
            int oi = k / 200, w = k - oi * 200, u = w * 2;
            uint p = (uint)f2bf(yt[oi * 400 + u]) | ((uint)f2bf(yt[oi * 400 + u + 1]) << 16);
            *(uint*)(z9 + (size_t)np * 204800 + (size_t)(o0 + oi) * 1600 + i * 400 + u) = p;
        }
    }
}

// ------- cbr: out = lrelu(res + BN(WT^T @ in + b)); res/out may alias -------
__global__ __launch_bounds__(256) void cbr_v2(
    const ushort* __restrict__ in /*quarter base bf16*/, const float* res /*quarter base*/,
    const float* __restrict__ WT /*[128c][128o]*/, const float* __restrict__ bias,
    const float* __restrict__ bnp, float* outp /*quarter base*/)
{
    __shared__ float ins[128 * 80];
    __shared__ float sc_l[128], of_l[128];
    const int np = blockIdx.y, tv0 = blockIdx.x * 80;
    if (threadIdx.x < 128) {
        int oo = threadIdx.x;
        float sc = bnp[oo] * rsqrtf(bnp[384 + oo] + 1e-5f);
        sc_l[oo] = sc;
        of_l[oo] = (bias[oo] - bnp[256 + oo]) * sc + bnp[128 + oo];
    }
    for (int i = threadIdx.x; i < 5120; i += 256) {
        int c = i / 40, w = i - c * 40;
        uint u = *(const uint*)(in + (size_t)np * 204800 + c * 1600 + tv0 + w * 2);
        ins[c * 80 + w * 2]     = __uint_as_float((u & 0xffffu) << 16);
        ins[c * 80 + w * 2 + 1] = __uint_as_float(u & 0xffff0000u);
    }
    __syncthreads();
    const int o = threadIdx.x & 63, cg = threadIdx.x >> 6;
    float acc0[20], acc1[20];
#pragma unroll
    for (int j = 0; j < 20; j++) { acc0[j] = 0.f; acc1[j] = 0.f; }
#pragma unroll 2
    for (int c = 0; c < 128; c++) {
        float w0 = WT[c * 128 + o], w1 = WT[c * 128 + o + 64];
        const float* yy = &ins[c * 80 + cg * 20];
#pragma unroll
        for (int jb = 0; jb < 5; jb++) {
            float4 q = *(const float4*)(yy + jb * 4);
            acc0[jb*4+0] += w0 * q.x; acc0[jb*4+1] += w0 * q.y;
            acc0[jb*4+2] += w0 * q.z; acc0[jb*4+3] += w0 * q.w;
            acc1[jb*4+0] += w1 * q.x; acc1[jb*4+1] += w1 * q.y;
            acc1[jb*4+2] += w1 * q.z; acc1[jb*4+3] += w1 * q.w;
        }
    }
    __syncthreads();
#pragma unroll
    for (int j = 0; j < 20; j++) {
        ins[o * 80 + cg * 20 + j] = acc0[j];
        ins[(o + 64) * 80 + cg * 20 + j] = acc1[j];
    }
    __syncthreads();
    for (int k = threadIdx.x; k < 2560; k += 256) {
        int row = k / 20, col4 = k - row * 20;
        size_t gofs = (size_t)np * 204800 + (size_t)row * 1600 + tv0 + col4 * 4;
        float4 rv = *(const float4*)(res + gofs);
        float sc = sc_l[row], of = of_l[row];
        float h0 = ins[row * 80 + col4 * 4 + 0] * sc + of + rv.x;
        float h1 = ins[row * 80 + col4 * 4 + 1] * sc + of + rv.y;
        float h2 = ins[row * 80 + col4 * 4 + 2] * sc + of + rv.z;
        float h3 = ins[row * 80 + col4 * 4 + 3] * sc + of + rv.w;
        float4 ov;
        ov.x = h0 > 0.f ? h0 : 0.1f * h0;
        ov.y = h1 > 0.f ? h1 : 0.1f * h1;
        ov.z = h2 > 0.f ? h2 : 0.1f * h2;
        ov.w = h3 > 0.f ? h3 : 0.1f * h3;
        *(float4*)(outp + gofs) = ov;
    }
}

extern "C" void kernel_launch(void* const* d_in, const int* in_sizes, int n_in,
                              void* d_out, int out_size, void* d_ws, size_t ws_size,
                              hipStream_t stream)
{
    (void)in_sizes; (void)n_in; (void)out_size; (void)ws_size;
    const float* x      = (const float*)d_in[0];
    const float* Wqk_s  = (const float*)d_in[1];
    const float* bqk_s  = (const float*)d_in[2];
    const float* alphas = (const float*)d_in[3];
    const float* att0s  = (const float*)d_in[4];
    const float* Wo_s   = (const float*)d_in[5];
    const float* bo_s   = (const float*)d_in[6];
    const float* bn_o_s = (const float*)d_in[7];
    const float* Wf_s   = (const float*)d_in[8];
    const float* bf_s   = (const float*)d_in[9];
    const float* bn_f_s = (const float*)d_in[10];
    const float* Wqk_t  = (const float*)d_in[11];
    const float* bqk_t  = (const float*)d_in[12];
    const float* alphat = (const float*)d_in[13];
    const float* att0t  = (const float*)d_in[14];
    const float* Wo_t   = (const float*)d_in[15];
    const float* bo_t   = (const float*)d_in[16];
    const float* bn_o_t = (const float*)d_in[17];
    const float* Wf_t   = (const float*)d_in[18];
    const float* bf_t   = (const float*)d_in[19];
    const float* bn_f_t = (const float*)d_in[20];

    float* out = (float*)d_out;
    const size_t CTV = 204800;
    // ws layout (bytes):
    //  [0, 78,643,200)  qk bf16 (full) — later reused: A=[0,39,321,600) G/H quarter bf16,
    //                                                   B=[39,321,600, 52,428,800) y1/z9 quarter bf16
    //  [78,643,200, 79,603,200)  attS fp32 (sums -> finalized)
    //  [79,603,200, 85,894,656)  attT fp32 (sums -> finalized)
    //  [85,894,656, 86,615,552)  WT (weights: bf16 Wo copies + fp32 others)
    ushort* qk   = (ushort*)d_ws;
    ushort* Gbuf = (ushort*)d_ws;
    ushort* y1q  = (ushort*)((char*)d_ws + 39321600);
    float*  attS = (float*)((char*)d_ws + 78643200);
    float*  attT = (float*)((char*)d_ws + 79603200);
    float*  WTb  = (float*)((char*)d_ws + 85894656);
    const ushort* WoS_bf = (const ushort*)WTb;
    float* WTfS  = WTb + 49152;
    const ushort* WoT_bf = (const ushort*)(WTb + 65536);
    float* WTfT  = WTb + 114688;
    float* WTqkS = WTb + 131072;
    float* WTqkT = WTb + 155648;

    wt_prep<<<704, 256, 0, stream>>>(Wo_s, Wf_s, Wo_t, Wf_t, Wqk_s, Wqk_t, WTb);
    hipMemsetAsync(attS, 0, 960000, stream);
    hipMemsetAsync(attT, 0, 6291456, stream);

    dim3 gqk(16, 128), gattp(24, 128), gt1(10, 32), gs2(8, 32), gcbr(20, 32);

    // ---- spatial ----
    qk_pe_v2<<<gqk, 256, 0, stream>>>(x, WTqkS, bqk_s, qk, 0);
    att_s_partial<<<gattp, 128, 0, stream>>>(qk, attS);
    att_s_final<<<938, 256, 0, stream>>>(attS, alphas, att0s);
    for (int h = 0; h < 4; h++) {
        size_t n0 = (size_t)h * 32;
        t1_mfma<<<gt1, 256, 0, stream>>>(x + n0 * CTV, WoS_bf, Gbuf);
        s2_kernel<<<gs2, 256, 0, stream>>>(Gbuf, attS + n0 * 1875, x + n0 * CTV,
                                           bn_o_s, bo_s, y1q);
        cbr_v2<<<gcbr, 256, 0, stream>>>(y1q, x + n0 * CTV, WTfS, bf_s, bn_f_s,
                                         out + n0 * CTV);
    }

    // ---- temporal ----
    qk_pe_v2<<<gqk, 256, 0, stream>>>(out, WTqkT, bqk_t, qk, 1);
    att_t_partial<<<gattp, 256, 0, stream>>>(qk, attT);
    att_t_final<<<6144, 256, 0, stream>>>(attT, alphat, att0t);
    for (int h = 0; h < 4; h++) {
        size_t n0 = (size_t)h * 32;
        t1_mfma<<<gt1, 256, 0, stream>>>(out + n0 * CTV, WoT_bf, Gbuf);
        t2_kernel<<<gs2, 256, 0, stream>>>(Gbuf, attT + n0 * 12288, out + n0 * CTV,
                                           bn_o_t, bo_t, y1q);
        cbr_v2<<<gcbr, 256, 0, stream>>>(y1q, out + n0 * CTV, WTfT, bf_t, bn_f_t,
                                         out + n0 * CTV);
    }
}

// Round 5
// 1755.204 us; speedup vs baseline: 2.1659x; 1.1523x over previous
//
#include <hip/hip_runtime.h>
#include <math.h>

// Dims: N=128, C=128, T=64, V=25, S=3, R=32; TV=1600, CTV=204800.
// qk layout: [n][tv][192r] bf16 (MFMA-friendly stores, uint2-friendly att reads)
// G/H bf16 [np][s][t][v][128o]. 4 quarters of 32 n.

typedef __attribute__((ext_vector_type(8))) short short8v;
typedef __attribute__((ext_vector_type(4))) float f32x4;

__device__ __forceinline__ ushort f2bf(float f) {
    uint b = __float_as_uint(f);
    uint r = b + 0x7fffu + ((b >> 16) & 1u);
    return (ushort)(r >> 16);
}
__device__ __forceinline__ float bf2f(ushort h) {
    return __uint_as_float(((uint)h) << 16);
}

__device__ __forceinline__ void fma25(float (&acc)[25], float w, const float* yy) {
#pragma unroll
    for (int jb = 0; jb < 6; jb++) {
        float4 q = *(const float4*)(yy + jb * 4);
        acc[jb*4+0] += w * q.x; acc[jb*4+1] += w * q.y;
        acc[jb*4+2] += w * q.z; acc[jb*4+3] += w * q.w;
    }
    acc[24] += w * yy[24];
}

__device__ __forceinline__ void fma25r(float* acc, float a, const float* g) {
#pragma unroll
    for (int v = 0; v < 25; v++) acc[v] += a * g[v];
}

// -------- weight prep: all bf16. ushort offsets in W16:
//  [0,49152) WoS_bf [3][128o][128c]   [49152,65536) WfS_bf [128o][128c]
//  [65536,114688) WoT_bf              [114688,131072) WfT_bf
//  [131072,155648) WqkS_bf [192r][128c]  [155648,180224) WqkT_bf
__global__ __launch_bounds__(256) void wt_prep(
    const float* __restrict__ Wo_s, const float* __restrict__ Wf_s,
    const float* __restrict__ Wo_t, const float* __restrict__ Wf_t,
    const float* __restrict__ Wqk_s, const float* __restrict__ Wqk_t,
    ushort* __restrict__ W16)
{
    int idx = blockIdx.x * 256 + threadIdx.x;
    if (idx >= 180224) return;
    float v;
    if (idx < 49152) {
        int s = idx / 16384, rem = idx % 16384, o = rem / 128, c = rem % 128;
        v = Wo_s[o * 384 + s * 128 + c];
    } else if (idx < 65536) {
        v = Wf_s[idx - 49152];
    } else if (idx < 114688) {
        int i = idx - 65536, s = i / 16384, rem = i % 16384, o = rem / 128, c = rem % 128;
        v = Wo_t[o * 384 + s * 128 + c];
    } else if (idx < 131072) {
        v = Wf_t[idx - 114688];
    } else if (idx < 155648) {
        v = Wqk_s[idx - 131072];
    } else {
        v = Wqk_t[idx - 155648];
    }
    W16[idx] = f2bf(v);
}

// -------- qk_pe (MFMA): qk[n][tv][192r] = Wqk @ (x + PE) + bias --------
__global__ __launch_bounds__(256) void qk_pe_mfma(
    const float* __restrict__ src, const ushort* __restrict__ Wbf, // [192r][128c]
    const float* __restrict__ bias, ushort* __restrict__ out, int pos_is_t)
{
    __shared__ __align__(16) ushort xT[160 * 136];  // [tv_local][c], pad 8
    const int n = blockIdx.y, tvb = blockIdx.x * 160;
    const float* sn = src + (size_t)n * 204800;
    for (int i = threadIdx.x; i < 2560; i += 256) {
        int tv4 = i % 40, cp = i / 40;
        float4 a = *(const float4*)(sn + (2 * cp) * 1600 + tvb + tv4 * 4);
        float4 b = *(const float4*)(sn + (2 * cp + 1) * 1600 + tvb + tv4 * 4);
        float dv = __expf(-0.14391156831212787f * (float)cp); // ln(1e4)/64, j=c>>1=cp
        float av[4] = { a.x, a.y, a.z, a.w };
        float bv[4] = { b.x, b.y, b.z, b.w };
#pragma unroll
        for (int e = 0; e < 4; e++) {
            int tv = tvb + tv4 * 4 + e;
            int tt = tv / 25;
            float pos = pos_is_t ? (float)tt : (float)(tv - tt * 25);
            float ang = pos * dv;
            uint p = (uint)f2bf(av[e] + __sinf(ang)) | ((uint)f2bf(bv[e] + __cosf(ang)) << 16);
            ((uint*)xT)[(tv4 * 4 + e) * 68 + cp] = p;
        }
    }
    __syncthreads();
    const int lane = threadIdx.x & 63, wave = threadIdx.x >> 6;
    const int l15 = lane & 15, kg = lane >> 4;
    const int rb = wave * 48;
    short8v wf[3][4];
#pragma unroll
    for (int nt = 0; nt < 3; nt++)
#pragma unroll
        for (int k = 0; k < 4; k++)
            wf[nt][k] = *(const short8v*)&Wbf[(rb + nt * 16 + l15) * 128 + k * 32 + kg * 8];
    float bsv[3];
#pragma unroll
    for (int nt = 0; nt < 3; nt++) bsv[nt] = bias[rb + nt * 16 + l15];
    ushort* on = out + (size_t)n * 307200;
    for (int mt = 0; mt < 10; mt++) {
        short8v af[4];
#pragma unroll
        for (int k = 0; k < 4; k++)
            af[k] = *(short8v*)&xT[(mt * 16 + l15) * 136 + k * 32 + kg * 8];
#pragma unroll
        for (int nt = 0; nt < 3; nt++) {
            f32x4 acc = {0.f, 0.f, 0.f, 0.f};
#pragma unroll
            for (int k = 0; k < 4; k++)
                acc = __builtin_amdgcn_mfma_f32_16x16x32_bf16(af[k], wf[nt][k], acc, 0, 0, 0);
#pragma unroll
            for (int rr = 0; rr < 4; rr++) {
                int tv = tvb + mt * 16 + kg * 4 + rr;
                on[(size_t)tv * 192 + rb + nt * 16 + l15] = f2bf(acc[rr] + bsv[nt]);
            }
        }
    }
}

// -------- att_s partial: sum[u,v] += sum_{4r,64t} Q K (qk layout [tv][192]) --------
__global__ __launch_bounds__(128) void att_s_partial(
    const ushort* __restrict__ qk, float* __restrict__ sum)
{
    __shared__ float qs[25 * 260];
    __shared__ float ks[25 * 260];
    const int s = blockIdx.x >> 3, rc = blockIdx.x & 7, n = blockIdx.y;
    const ushort* qkn = qk + (size_t)n * 307200;
    const int r0 = s * 32 + rc * 4;
    for (int tv = threadIdx.x; tv < 1600; tv += 128) {
        uint2 uq = *(const uint2*)(qkn + (size_t)tv * 192 + r0);
        uint2 uk = *(const uint2*)(qkn + (size_t)tv * 192 + r0 + 96);
        int t = tv / 25, u = tv - t * 25;
        float* qp = &qs[u * 260 + t];
        float* kp = &ks[u * 260 + t];
        qp[0]   = bf2f((ushort)(uq.x & 0xffffu));
        qp[64]  = bf2f((ushort)(uq.x >> 16));
        qp[128] = bf2f((ushort)(uq.y & 0xffffu));
        qp[192] = bf2f((ushort)(uq.y >> 16));
        kp[0]   = bf2f((ushort)(uk.x & 0xffffu));
        kp[64]  = bf2f((ushort)(uk.x >> 16));
        kp[128] = bf2f((ushort)(uk.y & 0xffffu));
        kp[192] = bf2f((ushort)(uk.y >> 16));
    }
    __syncthreads();
    if (threadIdx.x < 125) {
        const int u = threadIdx.x / 5, vg = threadIdx.x % 5;
        float acc[5] = {0.f, 0.f, 0.f, 0.f, 0.f};
        for (int p4 = 0; p4 < 64; p4++) {
            float4 qv = *(const float4*)&qs[u * 260 + p4 * 4];
#pragma unroll
            for (int j = 0; j < 5; j++) {
                float4 kv = *(const float4*)&ks[(vg * 5 + j) * 260 + p4 * 4];
                acc[j] += qv.x * kv.x + qv.y * kv.y + qv.z * kv.z + qv.w * kv.w;
            }
        }
        float* dst = sum + (size_t)(n * 3 + s) * 625 + u * 25 + vg * 5;
#pragma unroll
        for (int j = 0; j < 5; j++) atomicAdd(dst + j, acc[j]);
    }
}

__global__ __launch_bounds__(256) void att_s_final(
    float* __restrict__ att, const float* __restrict__ alphas,
    const float* __restrict__ att0)
{
    int idx = blockIdx.x * 256 + threadIdx.x;
    if (idx >= 240000) return;
    int rem = idx % 1875, s = rem / 625, uv = rem - s * 625;
    att[idx] = tanhf(att[idx] * (1.0f / 2048.0f)) * alphas[s] + att0[s * 625 + uv];
}

// -------- att_t partial (qk layout [tv][192]) --------
__global__ __launch_bounds__(256) void att_t_partial(
    const ushort* __restrict__ qk, float* __restrict__ sum)
{
    __shared__ float qs[100 * 68];
    __shared__ float ks[100 * 68];
    const int s = blockIdx.x >> 3, rc = blockIdx.x & 7, n = blockIdx.y;
    const ushort* qkn = qk + (size_t)n * 307200;
    const int r0 = s * 32 + rc * 4;
    for (int tv = threadIdx.x; tv < 1600; tv += 256) {
        uint2 uq = *(const uint2*)(qkn + (size_t)tv * 192 + r0);
        uint2 uk = *(const uint2*)(qkn + (size_t)tv * 192 + r0 + 96);
        int t = tv / 25, v = tv - t * 25;
        float* qp = &qs[v * 68 + t];
        float* kp = &ks[v * 68 + t];
        qp[0]         = bf2f((ushort)(uq.x & 0xffffu));
        qp[25 * 68]   = bf2f((ushort)(uq.x >> 16));
        qp[50 * 68]   = bf2f((ushort)(uq.y & 0xffffu));
        qp[75 * 68]   = bf2f((ushort)(uq.y >> 16));
        kp[0]         = bf2f((ushort)(uk.x & 0xffffu));
        kp[25 * 68]   = bf2f((ushort)(uk.x >> 16));
        kp[50 * 68]   = bf2f((ushort)(uk.y & 0xffffu));
        kp[75 * 68]   = bf2f((ushort)(uk.y >> 16));
    }
    __syncthreads();
    const int t0 = (threadIdx.x >> 4) * 4, q0 = (threadIdx.x & 15) * 4;
    float acc[4][4];
#pragma unroll
    for (int i = 0; i < 4; i++)
#pragma unroll
        for (int j = 0; j < 4; j++) acc[i][j] = 0.f;
    for (int rv = 0; rv < 100; rv++) {
        float4 qv = *(const float4*)&qs[rv * 68 + t0];
        float4 kv = *(const float4*)&ks[rv * 68 + q0];
        float qa[4] = { qv.x, qv.y, qv.z, qv.w };
        float ka[4] = { kv.x, kv.y, kv.z, kv.w };
#pragma unroll
        for (int i = 0; i < 4; i++)
#pragma unroll
            for (int j = 0; j < 4; j++) acc[i][j] += qa[i] * ka[j];
    }
    float* dst = sum + (size_t)(n * 3 + s) * 4096;
#pragma unroll
    for (int i = 0; i < 4; i++)
#pragma unroll
        for (int j = 0; j < 4; j++)
            atomicAdd(dst + (t0 + i) * 64 + q0 + j, acc[i][j]);
}

__global__ __launch_bounds__(256) void att_t_final(
    float* __restrict__ att, const float* __restrict__ alphat,
    const float* __restrict__ att0)
{
    int idx = blockIdx.x * 256 + threadIdx.x;
    if (idx >= 1572864) return;
    int rem = idx % 12288, s = rem / 4096, tq = rem - s * 4096;
    att[idx] = tanhf(att[idx] * (1.0f / 800.0f)) * alphat[s] + att0[s * 4096 + tq];
}

// ------- t1 (MFMA): G[np][s][t][v][128o] bf16 = sum_c Wbf[s][o][c] * src[c][tv] -------
__global__ __launch_bounds__(256) void t1_mfma(
    const float* __restrict__ src /*quarter base*/,
    const ushort* __restrict__ Wbf /*[3][128o][128c] bf16*/,
    ushort* __restrict__ G)
{
    __shared__ __align__(16) ushort xT[160 * 136];
    __shared__ __align__(16) ushort Ws[128 * 136];
    const int np = blockIdx.y, tvb = blockIdx.x * 160;
    const float* sn = src + (size_t)np * 204800;
    for (int i = threadIdx.x; i < 2560; i += 256) {
        int tv4 = i % 40, cp = i / 40;
        float4 a = *(const float4*)(sn + (2 * cp) * 1600 + tvb + tv4 * 4);
        float4 b = *(const float4*)(sn + (2 * cp + 1) * 1600 + tvb + tv4 * 4);
        float av[4] = { a.x, a.y, a.z, a.w };
        float bv[4] = { b.x, b.y, b.z, b.w };
#pragma unroll
        for (int e = 0; e < 4; e++) {
            uint p = (uint)f2bf(av[e]) | ((uint)f2bf(bv[e]) << 16);
            ((uint*)xT)[(tv4 * 4 + e) * 68 + cp] = p;
        }
    }
    __syncthreads();
    const int lane = threadIdx.x & 63, wave = threadIdx.x >> 6;
    const int l15 = lane & 15, kg = lane >> 4;
    const int o_base = wave * 32;
    for (int s = 0; s < 3; s++) {
        for (int i = threadIdx.x; i < 2048; i += 256) {
            int o = i >> 4, seg = i & 15;
            uint4 wv = *(const uint4*)(Wbf + s * 16384 + o * 128 + seg * 8);
            *(uint4*)&Ws[o * 136 + seg * 8] = wv;
        }
        __syncthreads();
        short8v bfr[2][4];
#pragma unroll
        for (int nt = 0; nt < 2; nt++)
#pragma unroll
            for (int k = 0; k < 4; k++)
                bfr[nt][k] = *(short8v*)&Ws[(o_base + nt * 16 + l15) * 136 + k * 32 + kg * 8];
        ushort* Gs = G + (size_t)(np * 3 + s) * 64 * 3200;
        for (int mt = 0; mt < 10; mt++) {
            short8v af[4];
#pragma unroll
            for (int k = 0; k < 4; k++)
                af[k] = *(short8v*)&xT[(mt * 16 + l15) * 136 + k * 32 + kg * 8];
            f32x4 acc0 = {0.f, 0.f, 0.f, 0.f};
            f32x4 acc1 = {0.f, 0.f, 0.f, 0.f};
#pragma unroll
            for (int k = 0; k < 4; k++) {
                acc0 = __builtin_amdgcn_mfma_f32_16x16x32_bf16(af[k], bfr[0][k], acc0, 0, 0, 0);
                acc1 = __builtin_amdgcn_mfma_f32_16x16x32_bf16(af[k], bfr[1][k], acc1, 0, 0, 0);
            }
#pragma unroll
            for (int r = 0; r < 4; r++) {
                int tvg = tvb + mt * 16 + kg * 4 + r;
                int t = tvg / 25, v = tvg - t * 25;
                Gs[t * 3200 + v * 128 + o_base + l15]      = f2bf(acc0[r]);
                Gs[t * 3200 + v * 128 + o_base + 16 + l15] = f2bf(acc1[r]);
            }
        }
        __syncthreads();
    }
}

// ------- S2: y1[o,t,v] = lrelu(x + BN(sum_{s,u} attS[s,u,v] H[o,s,t,u])) (bf16 out) -------
__global__ __launch_bounds__(256) void s2_kernel(
    const ushort* __restrict__ H, const float* __restrict__ attS /*quarter base*/,
    const float* __restrict__ xres /*quarter base*/, const float* __restrict__ bnp,
    const float* __restrict__ bo, ushort* __restrict__ y1)
{
    __shared__ float aS[3 * 25 * 28];
    __shared__ ushort Hc[16 * 408];
    __shared__ float xst[16 * 400];
    const int np = blockIdx.y, o0 = blockIdx.x * 16;
    const int o = threadIdx.x >> 4, tl = threadIdx.x & 15;
    const int o_act = o0 + o;
    float scale = bnp[o_act] * rsqrtf(bnp[384 + o_act] + 1e-5f);
    float off = (bo[o_act] - bnp[256 + o_act]) * scale + bnp[128 + o_act];
    for (int i = threadIdx.x; i < 1875; i += 256) {
        int s = i / 625, rem = i - s * 625, u = rem / 25, v = rem - u * 25;
        aS[(s * 25 + u) * 28 + v] = attS[(size_t)np * 1875 + i];
    }
    for (int tc = 0; tc < 4; tc++) {
        __syncthreads();
        for (int i = threadIdx.x; i < 1600; i += 256) {
            int oi = i / 100, w4 = i - oi * 100;
            *(float4*)&xst[oi * 400 + w4 * 4] =
                *(const float4*)(xres + (size_t)np * 204800 + (size_t)(o0 + oi) * 1600 + tc * 400 + w4 * 4);
        }
        float acc[25];
#pragma unroll
        for (int v = 0; v < 25; v++) acc[v] = 0.f;
        for (int s = 0; s < 3; s++) {
            __syncthreads();
            for (int i = threadIdx.x; i < 3200; i += 256) {
                int t = i / 200, rem = i - t * 200, v = rem / 8, w = rem - v * 8;
                uint val = *(const uint*)(H + ((size_t)(np * 3 + s) * 64 + tc * 16 + t) * 3200 + v * 128 + o0 + w * 2);
                ((uint*)Hc)[t * 204 + v * 8 + w] = val;
            }
            __syncthreads();
            float h[25];
#pragma unroll
            for (int u = 0; u < 25; u++)
                h[u] = __uint_as_float(((uint)Hc[tl * 408 + u * 16 + o]) << 16);
            const float* as = &aS[s * 25 * 28];
#pragma unroll
            for (int u = 0; u < 25; u++) fma25(acc, h[u], as + u * 28);
        }
        __syncthreads();
#pragma unroll
        for (int v = 0; v < 25; v++) {
            float rr = xst[o * 400 + tl * 25 + v] + (acc[v] * scale + off);
            rr = rr > 0.f ? rr : 0.1f * rr;
            xst[o * 400 + tl * 25 + v] = rr;
        }
        __syncthreads();
        for (int i = threadIdx.x; i < 3200; i += 256) {
            int oi = i / 200, w = i - oi * 200, u = w * 2;
            uint p = (uint)f2bf(xst[oi * 400 + u]) | ((uint)f2bf(xst[oi * 400 + u + 1]) << 16);
            *(uint*)(y1 + (size_t)np * 204800 + (size_t)(o0 + oi) * 1600 + tc * 400 + u) = p;
        }
    }
}

// ------- T2: z9[o,q,v] = lrelu(y + BN(sum_{s,t} attT[s,t,q] G[o,s,t,v])) (bf16 out) -------
__global__ __launch_bounds__(256) void t2_kernel(
    const ushort* __restrict__ G, const float* __restrict__ attT /*quarter base*/,
    const float* __restrict__ yres /*quarter base*/, const float* __restrict__ bnp,
    const float* __restrict__ bo, ushort* __restrict__ z9)
{
    __shared__ float aT[16 * 64];
    __shared__ ushort Gc[16 * 408];
    __shared__ float yt[16 * 400];
    const int np = blockIdx.y, o0 = blockIdx.x * 16;
    const int o = threadIdx.x >> 4, qh = threadIdx.x & 15;
    const int o_act = o0 + o;
    float scale = bnp[o_act] * rsqrtf(bnp[384 + o_act] + 1e-5f);
    float off = (bo[o_act] - bnp[256 + o_act]) * scale + bnp[128 + o_act];
    float acc[4][25];
#pragma unroll
    for (int i = 0; i < 4; i++)
#pragma unroll
        for (int v = 0; v < 25; v++) acc[i][v] = 0.f;
    for (int s = 0; s < 3; s++) {
        for (int tc = 0; tc < 4; tc++) {
            __syncthreads();
            for (int i = threadIdx.x; i < 1024; i += 256)
                aT[i] = attT[(size_t)np * 12288 + s * 4096 + tc * 1024 + i];
            for (int i = threadIdx.x; i < 3200; i += 256) {
                int t = i / 200, rem = i - t * 200, v = rem / 8, w = rem - v * 8;
                uint val = *(const uint*)(G + ((size_t)(np * 3 + s) * 64 + tc * 16 + t) * 3200 + v * 128 + o0 + w * 2);
                ((uint*)Gc)[t * 204 + v * 8 + w] = val;
            }
            __syncthreads();
            for (int tt = 0; tt < 16; tt++) {
                float gv[25];
#pragma unroll
                for (int v = 0; v < 25; v++)
                    gv[v] = __uint_as_float(((uint)Gc[tt * 408 + v * 16 + o]) << 16);
#pragma unroll
                for (int i = 0; i < 4; i++) {
                    float a = aT[tt * 64 + qh + i * 16];
                    fma25r(acc[i], a, gv);
                }
            }
        }
    }
#pragma unroll
    for (int i = 0; i < 4; i++) {
        __syncthreads();
        for (int k = threadIdx.x; k < 1600; k += 256) {
            int oi = k / 100, w4 = k - oi * 100;
            *(float4*)&yt[oi * 400 + w4 * 4] =
                *(const float4*)(yres + (size_t)np * 204800 + (size_t)(o0 + oi) * 1600 + i * 400 + w4 * 4);
        }
        __syncthreads();
#pragma unroll
        for (int v = 0; v < 25; v++) {
            float rr = yt[o * 400 + qh * 25 + v] + (acc[i][v] * scale + off);
            rr = rr > 0.f ? rr : 0.1f * rr;
            yt[o * 400 + qh * 25 + v] = rr;
        }
        __syncthreads();
        for (int k = threadIdx.x; k < 3200; k += 256) {
            int oi = k / 200, w = k - oi * 200, u = w * 2;
            uint p = (uint)f2bf(yt[oi * 400 + u]) | ((uint)f2bf(yt[oi * 400 + u + 1]) << 16);
            *(uint*)(z9 + (size_t)np * 204800 + (size_t)(o0 + oi) * 1600 + i * 400 + u) = p;
        }
    }
}

// ------- cbr (MFMA): out = lrelu(res + BN(W @ in + b)); res/out may alias -------
__global__ __launch_bounds__(256) void cbr_mfma(
    const ushort* __restrict__ in /*quarter base bf16*/, const float* res,
    const ushort* __restrict__ Wbf /*[128o][128c] bf16*/, const float* __restrict__ bias,
    const float* __restrict__ bnp, float* outp)
{
    __shared__ __align__(16) ushort xT[160 * 136];
    __shared__ float sc_l[128], of_l[128];
    const int np = blockIdx.y, tvb = blockIdx.x * 160;
    if (threadIdx.x < 128) {
        int o = threadIdx.x;
        float sc = bnp[o] * rsqrtf(bnp[384 + o] + 1e-5f);
        sc_l[o] = sc;
        of_l[o] = (bias[o] - bnp[256 + o]) * sc + bnp[128 + o];
    }
    const ushort* inn = in + (size_t)np * 204800;
    for (int i = threadIdx.x; i < 2560; i += 256) {
        int tv4 = i % 40, cp = i / 40;
        uint2 ua = *(const uint2*)(inn + (2 * cp) * 1600 + tvb + tv4 * 4);
        uint2 ub = *(const uint2*)(inn + (2 * cp + 1) * 1600 + tvb + tv4 * 4);
        uint* dst = (uint*)xT + (tv4 * 4) * 68 + cp;
        dst[0]      = (ua.x & 0xffffu) | (ub.x << 16);
        dst[68]     = (ua.x >> 16) | (ub.x & 0xffff0000u);
        dst[2 * 68] = (ua.y & 0xffffu) | (ub.y << 16);
        dst[3 * 68] = (ua.y >> 16) | (ub.y & 0xffff0000u);
    }
    __syncthreads();
    const int lane = threadIdx.x & 63, wave = threadIdx.x >> 6;
    const int l15 = lane & 15, kg = lane >> 4;
    const int ob = wave * 32;
    short8v af[2][4];
#pragma unroll
    for (int mt = 0; mt < 2; mt++)
#pragma unroll
        for (int k = 0; k < 4; k++)
            af[mt][k] = *(const short8v*)&Wbf[(ob + mt * 16 + l15) * 128 + k * 32 + kg * 8];
    for (int nt = 0; nt < 10; nt++) {
        short8v bfg[4];
#pragma unroll
        for (int k = 0; k < 4; k++)
            bfg[k] = *(short8v*)&xT[(nt * 16 + l15) * 136 + k * 32 + kg * 8];
        f32x4 acc0 = {0.f, 0.f, 0.f, 0.f};
        f32x4 acc1 = {0.f, 0.f, 0.f, 0.f};
#pragma unroll
        for (int k = 0; k < 4; k++) {
            acc0 = __builtin_amdgcn_mfma_f32_16x16x32_bf16(af[0][k], bfg[k], acc0, 0, 0, 0);
            acc1 = __builtin_amdgcn_mfma_f32_16x16x32_bf16(af[1][k], bfg[k], acc1, 0, 0, 0);
        }
        int tv = tvb + nt * 16 + l15;
#pragma unroll
        for (int rr = 0; rr < 4; rr++) {
            {
                int o = ob + kg * 4 + rr;
                size_t idx = (size_t)np * 204800 + (size_t)o * 1600 + tv;
                float h = acc0[rr] * sc_l[o] + of_l[o] + res[idx];
                outp[idx] = h > 0.f ? h : 0.1f * h;
            }
            {
                int o = ob + 16 + kg * 4 + rr;
                size_t idx = (size_t)np * 204800 + (size_t)o * 1600 + tv;
                float h = acc1[rr] * sc_l[o] + of_l[o] + res[idx];
                outp[idx] = h > 0.f ? h : 0.1f * h;
            }
        }
    }
}

extern "C" void kernel_launch(void* const* d_in, const int* in_sizes, int n_in,
                              void* d_out, int out_size, void* d_ws, size_t ws_size,
                              hipStream_t stream)
{
    (void)in_sizes; (void)n_in; (void)out_size; (void)ws_size;
    const float* x      = (const float*)d_in[0];
    const float* Wqk_s  = (const float*)d_in[1];
    const float* bqk_s  = (const float*)d_in[2];
    const float* alphas = (const float*)d_in[3];
    const float* att0s  = (const float*)d_in[4];
    const float* Wo_s   = (const float*)d_in[5];
    const float* bo_s   = (const float*)d_in[6];
    const float* bn_o_s = (const float*)d_in[7];
    const float* Wf_s   = (const float*)d_in[8];
    const float* bf_s   = (const float*)d_in[9];
    const float* bn_f_s = (const float*)d_in[10];
    const float* Wqk_t  = (const float*)d_in[11];
    const float* bqk_t  = (const float*)d_in[12];
    const float* alphat = (const float*)d_in[13];
    const float* att0t  = (const float*)d_in[14];
    const float* Wo_t   = (const float*)d_in[15];
    const float* bo_t   = (const float*)d_in[16];
    const float* bn_o_t = (const float*)d_in[17];
    const float* Wf_t   = (const float*)d_in[18];
    const float* bf_t   = (const float*)d_in[19];
    const float* bn_f_t = (const float*)d_in[20];

    float* out = (float*)d_out;
    const size_t CTV = 204800;
    // ws layout (bytes):
    //  [0, 78,643,200)  qk bf16 [n][1600tv][192r] — later reused:
    //       A=[0,39,321,600) G/H quarter bf16, B=[39,321,600,52,428,800) y1/z9 quarter
    //  [78,643,200, 79,603,200)  attS fp32
    //  [79,603,200, 85,894,656)  attT fp32
    //  [85,894,656, +360,448)    W16 bf16 weight copies
    ushort* qk   = (ushort*)d_ws;
    ushort* Gbuf = (ushort*)d_ws;
    ushort* y1q  = (ushort*)((char*)d_ws + 39321600);
    float*  attS = (float*)((char*)d_ws + 78643200);
    float*  attT = (float*)((char*)d_ws + 79603200);
    ushort* W16  = (ushort*)((char*)d_ws + 85894656);
    const ushort* WoS_bf  = W16;
    const ushort* WfS_bf  = W16 + 49152;
    const ushort* WoT_bf  = W16 + 65536;
    const ushort* WfT_bf  = W16 + 114688;
    const ushort* WqkS_bf = W16 + 131072;
    const ushort* WqkT_bf = W16 + 155648;

    wt_prep<<<704, 256, 0, stream>>>(Wo_s, Wf_s, Wo_t, Wf_t, Wqk_s, Wqk_t, W16);
    hipMemsetAsync(attS, 0, 960000, stream);
    hipMemsetAsync(attT, 0, 6291456, stream);

    dim3 gqk(10, 128), gattp(24, 128), gt1(10, 32), gs2(8, 32), gcbr(10, 32);

    // ---- spatial ----
    qk_pe_mfma<<<gqk, 256, 0, stream>>>(x, WqkS_bf, bqk_s, qk, 0);
    att_s_partial<<<gattp, 128, 0, stream>>>(qk, attS);
    att_s_final<<<938, 256, 0, stream>>>(attS, alphas, att0s);
    for (int h = 0; h < 4; h++) {
        size_t n0 = (size_t)h * 32;
        t1_mfma<<<gt1, 256, 0, stream>>>(x + n0 * CTV, WoS_bf, Gbuf);
        s2_kernel<<<gs2, 256, 0, stream>>>(Gbuf, attS + n0 * 1875, x + n0 * CTV,
                                           bn_o_s, bo_s, y1q);
        cbr_mfma<<<gcbr, 256, 0, stream>>>(y1q, x + n0 * CTV, WfS_bf, bf_s, bn_f_s,
                                           out + n0 * CTV);
    }

    // ---- temporal ----
    qk_pe_mfma<<<gqk, 256, 0, stream>>>(out, WqkT_bf, bqk_t, qk, 1);
    att_t_partial<<<gattp, 256, 0, stream>>>(qk, attT);
    att_t_final<<<6144, 256, 0, stream>>>(attT, alphat, att0t);
    for (int h = 0; h < 4; h++) {
        size_t n0 = (size_t)h * 32;
        t1_mfma<<<gt1, 256, 0, stream>>>(out + n0 * CTV, WoT_bf, Gbuf);
        t2_kernel<<<gs2, 256, 0, stream>>>(Gbuf, attT + n0 * 12288, out + n0 * CTV,
                                           bn_o_t, bo_t, y1q);
        cbr_mfma<<<gcbr, 256, 0, stream>>>(y1q, out + n0 * CTV, WfT_bf, bf_t, bn_f_t,
                                           out + n0 * CTV);
    }
}

// Round 6
// 1486.812 us; speedup vs baseline: 2.5569x; 1.1805x over previous
//
#include <hip/hip_runtime.h>
#include <math.h>

// Dims: N=128, C=128, T=64, V=25, S=3, R=32; TV=1600, CTV=204800.
// qk layout: [n][192r][1600tv] bf16 (r-major: coalesced att reads).
// G/H bf16 [np][s][t][v][128o]. 4 quarters of 32 n.
// att_s/att_t: one MFMA block per (s,n), fused tanh epilogue, no atomics.

typedef __attribute__((ext_vector_type(8))) short short8v;
typedef __attribute__((ext_vector_type(4))) float f32x4;

__device__ __forceinline__ ushort f2bf(float f) {
    uint b = __float_as_uint(f);
    uint r = b + 0x7fffu + ((b >> 16) & 1u);
    return (ushort)(r >> 16);
}
__device__ __forceinline__ float bf2f(ushort h) {
    return __uint_as_float(((uint)h) << 16);
}

__device__ __forceinline__ void fma25(float (&acc)[25], float w, const float* yy) {
#pragma unroll
    for (int jb = 0; jb < 6; jb++) {
        float4 q = *(const float4*)(yy + jb * 4);
        acc[jb*4+0] += w * q.x; acc[jb*4+1] += w * q.y;
        acc[jb*4+2] += w * q.z; acc[jb*4+3] += w * q.w;
    }
    acc[24] += w * yy[24];
}

__device__ __forceinline__ void fma25r(float* acc, float a, const float* g) {
#pragma unroll
    for (int v = 0; v < 25; v++) acc[v] += a * g[v];
}

// -------- weight prep: all bf16. ushort offsets in W16:
//  [0,49152) WoS_bf [3][128o][128c]   [49152,65536) WfS_bf [128o][128c]
//  [65536,114688) WoT_bf              [114688,131072) WfT_bf
//  [131072,155648) WqkS_bf [192r][128c]  [155648,180224) WqkT_bf
__global__ __launch_bounds__(256) void wt_prep(
    const float* __restrict__ Wo_s, const float* __restrict__ Wf_s,
    const float* __restrict__ Wo_t, const float* __restrict__ Wf_t,
    const float* __restrict__ Wqk_s, const float* __restrict__ Wqk_t,
    ushort* __restrict__ W16)
{
    int idx = blockIdx.x * 256 + threadIdx.x;
    if (idx >= 180224) return;
    float v;
    if (idx < 49152) {
        int s = idx / 16384, rem = idx % 16384, o = rem / 128, c = rem % 128;
        v = Wo_s[o * 384 + s * 128 + c];
    } else if (idx < 65536) {
        v = Wf_s[idx - 49152];
    } else if (idx < 114688) {
        int i = idx - 65536, s = i / 16384, rem = i % 16384, o = rem / 128, c = rem % 128;
        v = Wo_t[o * 384 + s * 128 + c];
    } else if (idx < 131072) {
        v = Wf_t[idx - 114688];
    } else if (idx < 155648) {
        v = Wqk_s[idx - 131072];
    } else {
        v = Wqk_t[idx - 155648];
    }
    W16[idx] = f2bf(v);
}

// -------- qk_pe (MFMA): qk[n][192r][1600tv] = Wqk @ (x + PE) + bias --------
__global__ __launch_bounds__(256) void qk_pe_mfma(
    const float* __restrict__ src, const ushort* __restrict__ Wbf, // [192r][128c]
    const float* __restrict__ bias, ushort* __restrict__ out, int pos_is_t)
{
    __shared__ __align__(16) ushort xT[160 * 136];  // [tv_local][c], pad 8
    __shared__ __align__(16) ushort exch[192 * 24]; // [r][16tv + 8 pad]
    const int n = blockIdx.y, tvb = blockIdx.x * 160;
    const float* sn = src + (size_t)n * 204800;
    for (int i = threadIdx.x; i < 2560; i += 256) {
        int tv4 = i % 40, cp = i / 40;
        float4 a = *(const float4*)(sn + (2 * cp) * 1600 + tvb + tv4 * 4);
        float4 b = *(const float4*)(sn + (2 * cp + 1) * 1600 + tvb + tv4 * 4);
        float dv = __expf(-0.14391156831212787f * (float)cp); // ln(1e4)/64, j=c>>1=cp
        float av[4] = { a.x, a.y, a.z, a.w };
        float bv[4] = { b.x, b.y, b.z, b.w };
#pragma unroll
        for (int e = 0; e < 4; e++) {
            int tv = tvb + tv4 * 4 + e;
            int tt = tv / 25;
            float pos = pos_is_t ? (float)tt : (float)(tv - tt * 25);
            float ang = pos * dv;
            uint p = (uint)f2bf(av[e] + __sinf(ang)) | ((uint)f2bf(bv[e] + __cosf(ang)) << 16);
            ((uint*)xT)[(tv4 * 4 + e) * 68 + cp] = p;
        }
    }
    __syncthreads();
    const int lane = threadIdx.x & 63, wave = threadIdx.x >> 6;
    const int l15 = lane & 15, kg = lane >> 4;
    const int rb = wave * 48;
    short8v wf[3][4];
#pragma unroll
    for (int nt = 0; nt < 3; nt++)
#pragma unroll
        for (int k = 0; k < 4; k++)
            wf[nt][k] = *(const short8v*)&Wbf[(rb + nt * 16 + l15) * 128 + k * 32 + kg * 8];
    float bsv[3];
#pragma unroll
    for (int nt = 0; nt < 3; nt++) bsv[nt] = bias[rb + nt * 16 + l15];
    ushort* on = out + (size_t)n * 307200;
    for (int mt = 0; mt < 10; mt++) {
        short8v af[4];
#pragma unroll
        for (int k = 0; k < 4; k++)
            af[k] = *(short8v*)&xT[(mt * 16 + l15) * 136 + k * 32 + kg * 8];
        f32x4 accs[3];
#pragma unroll
        for (int nt = 0; nt < 3; nt++) {
            f32x4 acc = {0.f, 0.f, 0.f, 0.f};
#pragma unroll
            for (int k = 0; k < 4; k++)
                acc = __builtin_amdgcn_mfma_f32_16x16x32_bf16(af[k], wf[nt][k], acc, 0, 0, 0);
            accs[nt] = acc;
        }
        __syncthreads();   // prior store-loop reads of exch complete
#pragma unroll
        for (int nt = 0; nt < 3; nt++)
#pragma unroll
            for (int rr = 0; rr < 4; rr++)
                exch[(rb + nt * 16 + l15) * 24 + kg * 4 + rr] = f2bf(accs[nt][rr] + bsv[nt]);
        __syncthreads();
        for (int i = threadIdx.x; i < 384; i += 256) {
            int r = i >> 1, hh = i & 1;
            *(uint4*)(on + (size_t)r * 1600 + tvb + mt * 16 + hh * 8) =
                *(const uint4*)&exch[r * 24 + hh * 8];
        }
    }
}

// -------- att_s (MFMA): att[u,v] = tanh(sum_{r,t} q[r,t,u]k[r,t,v] /2048)*a + att0 --------
__global__ __launch_bounds__(256) void att_s_mfma(
    const ushort* __restrict__ qk, const float* __restrict__ alphas,
    const float* __restrict__ att0, float* __restrict__ att)
{
    __shared__ __align__(16) ushort Qs[32 * 520];   // [u][k = rl*64 + t], rows 25..31 junk
    __shared__ __align__(16) ushort Ks[32 * 520];
    const int s = blockIdx.x, n = blockIdx.y;
    const ushort* qb = qk + (size_t)n * 307200 + (size_t)(s * 32) * 1600;
    const ushort* kb = qb + 96 * 1600;
    const int lane = threadIdx.x & 63, wave = threadIdx.x >> 6;
    const int l15 = lane & 15, kg = lane >> 4;
    const int mt = wave >> 1, nt = wave & 1;
    f32x4 acc = {0.f, 0.f, 0.f, 0.f};
    for (int rc = 0; rc < 4; rc++) {
        __syncthreads();
        for (int i = threadIdx.x; i < 6400; i += 256) {
            int rl = i / 800, j = i - rl * 800;
            uint uq = *(const uint*)(qb + (rc * 8 + rl) * 1600 + j * 2);
            uint uk = *(const uint*)(kb + (rc * 8 + rl) * 1600 + j * 2);
            int tv = j * 2;
            int t0 = tv / 25, u0 = tv - t0 * 25;
            int t1 = (tv + 1) / 25, u1 = (tv + 1) - t1 * 25;
            Qs[u0 * 520 + rl * 64 + t0] = (ushort)(uq & 0xffffu);
            Qs[u1 * 520 + rl * 64 + t1] = (ushort)(uq >> 16);
            Ks[u0 * 520 + rl * 64 + t0] = (ushort)(uk & 0xffffu);
            Ks[u1 * 520 + rl * 64 + t1] = (ushort)(uk >> 16);
        }
        __syncthreads();
#pragma unroll
        for (int ks = 0; ks < 16; ks++) {
            short8v a = *(const short8v*)&Qs[(mt * 16 + l15) * 520 + ks * 32 + kg * 8];
            short8v b = *(const short8v*)&Ks[(nt * 16 + l15) * 520 + ks * 32 + kg * 8];
            acc = __builtin_amdgcn_mfma_f32_16x16x32_bf16(a, b, acc, 0, 0, 0);
        }
    }
    float alpha = alphas[s];
#pragma unroll
    for (int rr = 0; rr < 4; rr++) {
        int u = mt * 16 + kg * 4 + rr, v = nt * 16 + l15;
        if (u < 25 && v < 25)
            att[(size_t)(n * 3 + s) * 625 + u * 25 + v] =
                tanhf(acc[rr] * (1.0f / 2048.0f)) * alpha + att0[s * 625 + u * 25 + v];
    }
}

// -------- att_t (MFMA): att[t,q] = tanh(sum_{r,v} q[r,t,v]k[r,q,v] /800)*a + att0 --------
__global__ __launch_bounds__(256) void att_t_mfma(
    const ushort* __restrict__ qk, const float* __restrict__ alphat,
    const float* __restrict__ att0, float* __restrict__ att)
{
    __shared__ __align__(16) ushort Qt[8 * 64 * 40]; // [rl][t][v pad 40] (pad zeroed)
    __shared__ __align__(16) ushort Kt[8 * 64 * 40];
    const int s = blockIdx.x, n = blockIdx.y;
    const ushort* qb = qk + (size_t)n * 307200 + (size_t)(s * 32) * 1600;
    const ushort* kb = qb + 96 * 1600;
    for (int i = threadIdx.x; i < 10240; i += 256) {
        ((uint*)Qt)[i] = 0u;
        ((uint*)Kt)[i] = 0u;
    }
    const int lane = threadIdx.x & 63, wave = threadIdx.x >> 6;
    const int l15 = lane & 15, kg = lane >> 4;
    const int mt = wave;
    f32x4 acc[4];
#pragma unroll
    for (int i = 0; i < 4; i++) acc[i] = (f32x4){0.f, 0.f, 0.f, 0.f};
    for (int rc = 0; rc < 4; rc++) {
        __syncthreads();
        for (int i = threadIdx.x; i < 6400; i += 256) {
            int rl = i / 800, j = i - rl * 800;
            uint uq = *(const uint*)(qb + (rc * 8 + rl) * 1600 + j * 2);
            uint uk = *(const uint*)(kb + (rc * 8 + rl) * 1600 + j * 2);
            int tv = j * 2;
            int t0 = tv / 25, v0 = tv - t0 * 25;
            int t1 = (tv + 1) / 25, v1 = (tv + 1) - t1 * 25;
            Qt[(rl * 64 + t0) * 40 + v0] = (ushort)(uq & 0xffffu);
            Qt[(rl * 64 + t1) * 40 + v1] = (ushort)(uq >> 16);
            Kt[(rl * 64 + t0) * 40 + v0] = (ushort)(uk & 0xffffu);
            Kt[(rl * 64 + t1) * 40 + v1] = (ushort)(uk >> 16);
        }
        __syncthreads();
#pragma unroll
        for (int rl = 0; rl < 8; rl++) {
            short8v a = *(const short8v*)&Qt[(rl * 64 + mt * 16 + l15) * 40 + kg * 8];
#pragma unroll
            for (int nq = 0; nq < 4; nq++) {
                short8v b = *(const short8v*)&Kt[(rl * 64 + nq * 16 + l15) * 40 + kg * 8];
                acc[nq] = __builtin_amdgcn_mfma_f32_16x16x32_bf16(a, b, acc[nq], 0, 0, 0);
            }
        }
    }
    float alpha = alphat[s];
#pragma unroll
    for (int nq = 0; nq < 4; nq++)
#pragma unroll
        for (int rr = 0; rr < 4; rr++) {
            int t = mt * 16 + kg * 4 + rr, q = nq * 16 + l15;
            att[(size_t)(n * 3 + s) * 4096 + t * 64 + q] =
                tanhf(acc[nq][rr] * (1.0f / 800.0f)) * alpha + att0[s * 4096 + t * 64 + q];
        }
}

// ------- t1 (MFMA): G[np][s][t][v][128o] bf16 = sum_c Wbf[s][o][c] * src[c][tv] -------
__global__ __launch_bounds__(256) void t1_mfma(
    const float* __restrict__ src /*quarter base*/,
    const ushort* __restrict__ Wbf /*[3][128o][128c] bf16*/,
    ushort* __restrict__ G)
{
    __shared__ __align__(16) ushort xT[160 * 136];
    __shared__ __align__(16) ushort Ws[128 * 136];
    const int np = blockIdx.y, tvb = blockIdx.x * 160;
    const float* sn = src + (size_t)np * 204800;
    for (int i = threadIdx.x; i < 2560; i += 256) {
        int tv4 = i % 40, cp = i / 40;
        float4 a = *(const float4*)(sn + (2 * cp) * 1600 + tvb + tv4 * 4);
        float4 b = *(const float4*)(sn + (2 * cp + 1) * 1600 + tvb + tv4 * 4);
        float av[4] = { a.x, a.y, a.z, a.w };
        float bv[4] = { b.x, b.y, b.z, b.w };
#pragma unroll
        for (int e = 0; e < 4; e++) {
            uint p = (uint)f2bf(av[e]) | ((uint)f2bf(bv[e]) << 16);
            ((uint*)xT)[(tv4 * 4 + e) * 68 + cp] = p;
        }
    }
    __syncthreads();
    const int lane = threadIdx.x & 63, wave = threadIdx.x >> 6;
    const int l15 = lane & 15, kg = lane >> 4;
    const int o_base = wave * 32;
    for (int s = 0; s < 3; s++) {
        for (int i = threadIdx.x; i < 2048; i += 256) {
            int o = i >> 4, seg = i & 15;
            uint4 wv = *(const uint4*)(Wbf + s * 16384 + o * 128 + seg * 8);
            *(uint4*)&Ws[o * 136 + seg * 8] = wv;
        }
        __syncthreads();
        short8v bfr[2][4];
#pragma unroll
        for (int nt = 0; nt < 2; nt++)
#pragma unroll
            for (int k = 0; k < 4; k++)
                bfr[nt][k] = *(short8v*)&Ws[(o_base + nt * 16 + l15) * 136 + k * 32 + kg * 8];
        ushort* Gs = G + (size_t)(np * 3 + s) * 64 * 3200;
        for (int mt = 0; mt < 10; mt++) {
            short8v af[4];
#pragma unroll
            for (int k = 0; k < 4; k++)
                af[k] = *(short8v*)&xT[(mt * 16 + l15) * 136 + k * 32 + kg * 8];
            f32x4 acc0 = {0.f, 0.f, 0.f, 0.f};
            f32x4 acc1 = {0.f, 0.f, 0.f, 0.f};
#pragma unroll
            for (int k = 0; k < 4; k++) {
                acc0 = __builtin_amdgcn_mfma_f32_16x16x32_bf16(af[k], bfr[0][k], acc0, 0, 0, 0);
                acc1 = __builtin_amdgcn_mfma_f32_16x16x32_bf16(af[k], bfr[1][k], acc1, 0, 0, 0);
            }
#pragma unroll
            for (int r = 0; r < 4; r++) {
                int tvg = tvb + mt * 16 + kg * 4 + r;
                int t = tvg / 25, v = tvg - t * 25;
                Gs[t * 3200 + v * 128 + o_base + l15]      = f2bf(acc0[r]);
                Gs[t * 3200 + v * 128 + o_base + 16 + l15] = f2bf(acc1[r]);
            }
        }
        __syncthreads();
    }
}

// ------- S2: y1[o,t,v] = lrelu(x + BN(sum_{s,u} attS[s,u,v] H[o,s,t,u])) (bf16 out) -------
__global__ __launch_bounds__(256) void s2_kernel(
    const ushort* __restrict__ H, const float* __restrict__ attS /*quarter base*/,
    const float* __restrict__ xres /*quarter base*/, const float* __restrict__ bnp,
    const float* __restrict__ bo, ushort* __restrict__ y1)
{
    __shared__ float aS[3 * 25 * 28];
    __shared__ ushort Hc[16 * 408];
    __shared__ float xst[16 * 400];
    const int np = blockIdx.y, o0 = blockIdx.x * 16;
    const int o = threadIdx.x >> 4, tl = threadIdx.x & 15;
    const int o_act = o0 + o;
    float scale = bnp[o_act] * rsqrtf(bnp[384 + o_act] + 1e-5f);
    float off = (bo[o_act] - bnp[256 + o_act]) * scale + bnp[128 + o_act];
    for (int i = threadIdx.x; i < 1875; i += 256) {
        int s = i / 625, rem = i - s * 625, u = rem / 25, v = rem - u * 25;
        aS[(s * 25 + u) * 28 + v] = attS[(size_t)np * 1875 + i];
    }
    for (int tc = 0; tc < 4; tc++) {
        __syncthreads();
        for (int i = threadIdx.x; i < 1600; i += 256) {
            int oi = i / 100, w4 = i - oi * 100;
            *(float4*)&xst[oi * 400 + w4 * 4] =
                *(const float4*)(xres + (size_t)np * 204800 + (size_t)(o0 + oi) * 1600 + tc * 400 + w4 * 4);
        }
        float acc[25];
#pragma unroll
        for (int v = 0; v < 25; v++) acc[v] = 0.f;
        for (int s = 0; s < 3; s++) {
            __syncthreads();
            for (int i = threadIdx.x; i < 3200; i += 256) {
                int t = i / 200, rem = i - t * 200, v = rem / 8, w = rem - v * 8;
                uint val = *(const uint*)(H + ((size_t)(np * 3 + s) * 64 + tc * 16 + t) * 3200 + v * 128 + o0 + w * 2);
                ((uint*)Hc)[t * 204 + v * 8 + w] = val;
            }
            __syncthreads();
            float h[25];
#pragma unroll
            for (int u = 0; u < 25; u++)
                h[u] = __uint_as_float(((uint)Hc[tl * 408 + u * 16 + o]) << 16);
            const float* as = &aS[s * 25 * 28];
#pragma unroll
            for (int u = 0; u < 25; u++) fma25(acc, h[u], as + u * 28);
        }
        __syncthreads();
#pragma unroll
        for (int v = 0; v < 25; v++) {
            float rr = xst[o * 400 + tl * 25 + v] + (acc[v] * scale + off);
            rr = rr > 0.f ? rr : 0.1f * rr;
            xst[o * 400 + tl * 25 + v] = rr;
        }
        __syncthreads();
        for (int i = threadIdx.x; i < 3200; i += 256) {
            int oi = i / 200, w = i - oi * 200, u = w * 2;
            uint p = (uint)f2bf(xst[oi * 400 + u]) | ((uint)f2bf(xst[oi * 400 + u + 1]) << 16);
            *(uint*)(y1 + (size_t)np * 204800 + (size_t)(o0 + oi) * 1600 + tc * 400 + u) = p;
        }
    }
}

// ------- T2: z9[o,q,v] = lrelu(y + BN(sum_{s,t} attT[s,t,q] G[o,s,t,v])) (bf16 out) -------
__global__ __launch_bounds__(256) void t2_kernel(
    const ushort* __restrict__ G, const float* __restrict__ attT /*quarter base*/,
    const float* __restrict__ yres /*quarter base*/, const float* __restrict__ bnp,
    const float* __restrict__ bo, ushort* __restrict__ z9)
{
    __shared__ float aT[16 * 64];
    __shared__ ushort Gc[16 * 408];
    __shared__ float yt[16 * 400];
    const int np = blockIdx.y, o0 = blockIdx.x * 16;
    const int o = threadIdx.x >> 4, qh = threadIdx.x & 15;
    const int o_act = o0 + o;
    float scale = bnp[o_act] * rsqrtf(bnp[384 + o_act] + 1e-5f);
    float off = (bo[o_act] - bnp[256 + o_act]) * scale + bnp[128 + o_act];
    float acc[4][25];
#pragma unroll
    for (int i = 0; i < 4; i++)
#pragma unroll
        for (int v = 0; v < 25; v++) acc[i][v] = 0.f;
    for (int s = 0; s < 3; s++) {
        for (int tc = 0; tc < 4; tc++) {
            __syncthreads();
            for (int i = threadIdx.x; i < 1024; i += 256)
                aT[i] = attT[(size_t)np * 12288 + s * 4096 + tc * 1024 + i];
            for (int i = threadIdx.x; i < 3200; i += 256) {
                int t = i / 200, rem = i - t * 200, v = rem / 8, w = rem - v * 8;
                uint val = *(const uint*)(G + ((size_t)(np * 3 + s) * 64 + tc * 16 + t) * 3200 + v * 128 + o0 + w * 2);
                ((uint*)Gc)[t * 204 + v * 8 + w] = val;
            }
            __syncthreads();
            for (int tt = 0; tt < 16; tt++) {
                float gv[25];
#pragma unroll
                for (int v = 0; v < 25; v++)
                    gv[v] = __uint_as_float(((uint)Gc[tt * 408 + v * 16 + o]) << 16);
#pragma unroll
                for (int i = 0; i < 4; i++) {
                    float a = aT[tt * 64 + qh + i * 16];
                    fma25r(acc[i], a, gv);
                }
            }
        }
    }
#pragma unroll
    for (int i = 0; i < 4; i++) {
        __syncthreads();
        for (int k = threadIdx.x; k < 1600; k += 256) {
            int oi = k / 100, w4 = k - oi * 100;
            *(float4*)&yt[oi * 400 + w4 * 4] =
                *(const float4*)(yres + (size_t)np * 204800 + (size_t)(o0 + oi) * 1600 + i * 400 + w4 * 4);
        }
        __syncthreads();
#pragma unroll
        for (int v = 0; v < 25; v++) {
            float rr = yt[o * 400 + qh * 25 + v] + (acc[i][v] * scale + off);
            rr = rr > 0.f ? rr : 0.1f * rr;
            yt[o * 400 + qh * 25 + v] = rr;
        }
        __syncthreads();
        for (int k = threadIdx.x; k < 3200; k += 256) {
            int oi = k / 200, w = k - oi * 200, u = w * 2;
            uint p = (uint)f2bf(yt[oi * 400 + u]) | ((uint)f2bf(yt[oi * 400 + u + 1]) << 16);
            *(uint*)(z9 + (size_t)np * 204800 + (size_t)(o0 + oi) * 1600 + i * 400 + u) = p;
        }
    }
}

// ------- cbr (MFMA): out = lrelu(res + BN(W @ in + b)); res/out may alias -------
__global__ __launch_bounds__(256) void cbr_mfma(
    const ushort* __restrict__ in /*quarter base bf16*/, const float* res,
    const ushort* __restrict__ Wbf /*[128o][128c] bf16*/, const float* __restrict__ bias,
    const float* __restrict__ bnp, float* outp)
{
    __shared__ __align__(16) ushort xT[160 * 136];
    __shared__ float sc_l[128], of_l[128];
    const int np = blockIdx.y, tvb = blockIdx.x * 160;
    if (threadIdx.x < 128) {
        int o = threadIdx.x;
        float sc = bnp[o] * rsqrtf(bnp[384 + o] + 1e-5f);
        sc_l[o] = sc;
        of_l[o] = (bias[o] - bnp[256 + o]) * sc + bnp[128 + o];
    }
    const ushort* inn = in + (size_t)np * 204800;
    for (int i = threadIdx.x; i < 2560; i += 256) {
        int tv4 = i % 40, cp = i / 40;
        uint2 ua = *(const uint2*)(inn + (2 * cp) * 1600 + tvb + tv4 * 4);
        uint2 ub = *(const uint2*)(inn + (2 * cp + 1) * 1600 + tvb + tv4 * 4);
        uint* dst = (uint*)xT + (tv4 * 4) * 68 + cp;
        dst[0]      = (ua.x & 0xffffu) | (ub.x << 16);
        dst[68]     = (ua.x >> 16) | (ub.x & 0xffff0000u);
        dst[2 * 68] = (ua.y & 0xffffu) | (ub.y << 16);
        dst[3 * 68] = (ua.y >> 16) | (ub.y & 0xffff0000u);
    }
    __syncthreads();
    const int lane = threadIdx.x & 63, wave = threadIdx.x >> 6;
    const int l15 = lane & 15, kg = lane >> 4;
    const int ob = wave * 32;
    short8v af[2][4];
#pragma unroll
    for (int mt = 0; mt < 2; mt++)
#pragma unroll
        for (int k = 0; k < 4; k++)
            af[mt][k] = *(const short8v*)&Wbf[(ob + mt * 16 + l15) * 128 + k * 32 + kg * 8];
    for (int nt = 0; nt < 10; nt++) {
        short8v bfg[4];
#pragma unroll
        for (int k = 0; k < 4; k++)
            bfg[k] = *(short8v*)&xT[(nt * 16 + l15) * 136 + k * 32 + kg * 8];
        f32x4 acc0 = {0.f, 0.f, 0.f, 0.f};
        f32x4 acc1 = {0.f, 0.f, 0.f, 0.f};
#pragma unroll
        for (int k = 0; k < 4; k++) {
            acc0 = __builtin_amdgcn_mfma_f32_16x16x32_bf16(af[0][k], bfg[k], acc0, 0, 0, 0);
            acc1 = __builtin_amdgcn_mfma_f32_16x16x32_bf16(af[1][k], bfg[k], acc1, 0, 0, 0);
        }
        int tv = tvb + nt * 16 + l15;
#pragma unroll
        for (int rr = 0; rr < 4; rr++) {
            {
                int o = ob + kg * 4 + rr;
                size_t idx = (size_t)np * 204800 + (size_t)o * 1600 + tv;
                float h = acc0[rr] * sc_l[o] + of_l[o] + res[idx];
                outp[idx] = h > 0.f ? h : 0.1f * h;
            }
            {
                int o = ob + 16 + kg * 4 + rr;
                size_t idx = (size_t)np * 204800 + (size_t)o * 1600 + tv;
                float h = acc1[rr] * sc_l[o] + of_l[o] + res[idx];
                outp[idx] = h > 0.f ? h : 0.1f * h;
            }
        }
    }
}

extern "C" void kernel_launch(void* const* d_in, const int* in_sizes, int n_in,
                              void* d_out, int out_size, void* d_ws, size_t ws_size,
                              hipStream_t stream)
{
    (void)in_sizes; (void)n_in; (void)out_size; (void)ws_size;
    const float* x      = (const float*)d_in[0];
    const float* Wqk_s  = (const float*)d_in[1];
    const float* bqk_s  = (const float*)d_in[2];
    const float* alphas = (const float*)d_in[3];
    const float* att0s  = (const float*)d_in[4];
    const float* Wo_s   = (const float*)d_in[5];
    const float* bo_s   = (const float*)d_in[6];
    const float* bn_o_s = (const float*)d_in[7];
    const float* Wf_s   = (const float*)d_in[8];
    const float* bf_s   = (const float*)d_in[9];
    const float* bn_f_s = (const float*)d_in[10];
    const float* Wqk_t  = (const float*)d_in[11];
    const float* bqk_t  = (const float*)d_in[12];
    const float* alphat = (const float*)d_in[13];
    const float* att0t  = (const float*)d_in[14];
    const float* Wo_t   = (const float*)d_in[15];
    const float* bo_t   = (const float*)d_in[16];
    const float* bn_o_t = (const float*)d_in[17];
    const float* Wf_t   = (const float*)d_in[18];
    const float* bf_t   = (const float*)d_in[19];
    const float* bn_f_t = (const float*)d_in[20];

    float* out = (float*)d_out;
    const size_t CTV = 204800;
    // ws layout (bytes):
    //  [0, 78,643,200)  qk bf16 [n][192r][1600tv] — later reused:
    //       A=[0,39,321,600) G/H quarter bf16, B=[39,321,600,52,428,800) y1/z9 quarter
    //  [78,643,200, 79,603,200)  attS fp32
    //  [79,603,200, 85,894,656)  attT fp32
    //  [85,894,656, +360,448)    W16 bf16 weight copies
    ushort* qk   = (ushort*)d_ws;
    ushort* Gbuf = (ushort*)d_ws;
    ushort* y1q  = (ushort*)((char*)d_ws + 39321600);
    float*  attS = (float*)((char*)d_ws + 78643200);
    float*  attT = (float*)((char*)d_ws + 79603200);
    ushort* W16  = (ushort*)((char*)d_ws + 85894656);
    const ushort* WoS_bf  = W16;
    const ushort* WfS_bf  = W16 + 49152;
    const ushort* WoT_bf  = W16 + 65536;
    const ushort* WfT_bf  = W16 + 114688;
    const ushort* WqkS_bf = W16 + 131072;
    const ushort* WqkT_bf = W16 + 155648;

    wt_prep<<<704, 256, 0, stream>>>(Wo_s, Wf_s, Wo_t, Wf_t, Wqk_s, Wqk_t, W16);

    dim3 gqk(10, 128), gatt(3, 128), gt1(10, 32), gs2(8, 32), gcbr(10, 32);

    // ---- spatial ----
    qk_pe_mfma<<<gqk, 256, 0, stream>>>(x, WqkS_bf, bqk_s, qk, 0);
    att_s_mfma<<<gatt, 256, 0, stream>>>(qk, alphas, att0s, attS);
    for (int h = 0; h < 4; h++) {
        size_t n0 = (size_t)h * 32;
        t1_mfma<<<gt1, 256, 0, stream>>>(x + n0 * CTV, WoS_bf, Gbuf);
        s2_kernel<<<gs2, 256, 0, stream>>>(Gbuf, attS + n0 * 1875, x + n0 * CTV,
                                           bn_o_s, bo_s, y1q);
        cbr_mfma<<<gcbr, 256, 0, stream>>>(y1q, x + n0 * CTV, WfS_bf, bf_s, bn_f_s,
                                           out + n0 * CTV);
    }

    // ---- temporal ----
    qk_pe_mfma<<<gqk, 256, 0, stream>>>(out, WqkT_bf, bqk_t, qk, 1);
    att_t_mfma<<<gatt, 256, 0, stream>>>(qk, alphat, att0t, attT);
    for (int h = 0; h < 4; h++) {
        size_t n0 = (size_t)h * 32;
        t1_mfma<<<gt1, 256, 0, stream>>>(out + n0 * CTV, WoT_bf, Gbuf);
        t2_kernel<<<gs2, 256, 0, stream>>>(Gbuf, attT + n0 * 12288, out + n0 * CTV,
                                           bn_o_t, bo_t, y1q);
        cbr_mfma<<<gcbr, 256, 0, stream>>>(y1q, out + n0 * CTV, WfT_bf, bf_t, bn_f_t,
                                           out + n0 * CTV);
    }
}

// Round 7
// 937.105 us; speedup vs baseline: 4.0568x; 1.5866x over previous
//
#include <hip/hip_runtime.h>
#include <math.h>

// Dims: N=128, C=128, T=64, V=25, S=3, R=32; TV=1600, CTV=204800.
// qk: [n][192r][1600tv] bf16. G/H: [np][s][t][v][128o] bf16.
// attS_bf: [n][32v][96k] bf16 (k=s*25+u, pads zeroed). attT_bf: [n][64q][192k] (k=s*64+t).
// pre: [np][1600tv][128o] bf16 = BN(att-conv), residual+lrelu fused into cbr stage.

typedef __attribute__((ext_vector_type(8))) short short8v;
typedef __attribute__((ext_vector_type(4))) float f32x4;

__device__ __forceinline__ ushort f2bf(float f) {
    uint b = __float_as_uint(f);
    uint r = b + 0x7fffu + ((b >> 16) & 1u);
    return (ushort)(r >> 16);
}
__device__ __forceinline__ float bf2f(ushort h) {
    return __uint_as_float(((uint)h) << 16);
}

// -------- weight prep (bf16 copies) --------
__global__ __launch_bounds__(256) void wt_prep(
    const float* __restrict__ Wo_s, const float* __restrict__ Wf_s,
    const float* __restrict__ Wo_t, const float* __restrict__ Wf_t,
    const float* __restrict__ Wqk_s, const float* __restrict__ Wqk_t,
    ushort* __restrict__ W16)
{
    int idx = blockIdx.x * 256 + threadIdx.x;
    if (idx >= 180224) return;
    float v;
    if (idx < 49152) {
        int s = idx / 16384, rem = idx % 16384, o = rem / 128, c = rem % 128;
        v = Wo_s[o * 384 + s * 128 + c];
    } else if (idx < 65536) {
        v = Wf_s[idx - 49152];
    } else if (idx < 114688) {
        int i = idx - 65536, s = i / 16384, rem = i % 16384, o = rem / 128, c = rem % 128;
        v = Wo_t[o * 384 + s * 128 + c];
    } else if (idx < 131072) {
        v = Wf_t[idx - 114688];
    } else if (idx < 155648) {
        v = Wqk_s[idx - 131072];
    } else {
        v = Wqk_t[idx - 155648];
    }
    W16[idx] = f2bf(v);
}

// -------- qk_pe (MFMA): qk[n][192r][1600tv] --------
__global__ __launch_bounds__(256) void qk_pe_mfma(
    const float* __restrict__ src, const ushort* __restrict__ Wbf,
    const float* __restrict__ bias, ushort* __restrict__ out, int pos_is_t)
{
    __shared__ __align__(16) ushort xT[160 * 136];
    __shared__ __align__(16) ushort exch[192 * 24];
    const int n = blockIdx.y, tvb = blockIdx.x * 160;
    const float* sn = src + (size_t)n * 204800;
    for (int i = threadIdx.x; i < 2560; i += 256) {
        int tv4 = i % 40, cp = i / 40;
        float4 a = *(const float4*)(sn + (2 * cp) * 1600 + tvb + tv4 * 4);
        float4 b = *(const float4*)(sn + (2 * cp + 1) * 1600 + tvb + tv4 * 4);
        float dv = __expf(-0.14391156831212787f * (float)cp);
        float av[4] = { a.x, a.y, a.z, a.w };
        float bv[4] = { b.x, b.y, b.z, b.w };
#pragma unroll
        for (int e = 0; e < 4; e++) {
            int tv = tvb + tv4 * 4 + e;
            int tt = tv / 25;
            float pos = pos_is_t ? (float)tt : (float)(tv - tt * 25);
            float ang = pos * dv;
            uint p = (uint)f2bf(av[e] + __sinf(ang)) | ((uint)f2bf(bv[e] + __cosf(ang)) << 16);
            ((uint*)xT)[(tv4 * 4 + e) * 68 + cp] = p;
        }
    }
    __syncthreads();
    const int lane = threadIdx.x & 63, wave = threadIdx.x >> 6;
    const int l15 = lane & 15, kg = lane >> 4;
    const int rb = wave * 48;
    short8v wf[3][4];
#pragma unroll
    for (int nt = 0; nt < 3; nt++)
#pragma unroll
        for (int k = 0; k < 4; k++)
            wf[nt][k] = *(const short8v*)&Wbf[(rb + nt * 16 + l15) * 128 + k * 32 + kg * 8];
    float bsv[3];
#pragma unroll
    for (int nt = 0; nt < 3; nt++) bsv[nt] = bias[rb + nt * 16 + l15];
    ushort* on = out + (size_t)n * 307200;
    for (int mt = 0; mt < 10; mt++) {
        short8v af[4];
#pragma unroll
        for (int k = 0; k < 4; k++)
            af[k] = *(short8v*)&xT[(mt * 16 + l15) * 136 + k * 32 + kg * 8];
        f32x4 accs[3];
#pragma unroll
        for (int nt = 0; nt < 3; nt++) {
            f32x4 acc = {0.f, 0.f, 0.f, 0.f};
#pragma unroll
            for (int k = 0; k < 4; k++)
                acc = __builtin_amdgcn_mfma_f32_16x16x32_bf16(af[k], wf[nt][k], acc, 0, 0, 0);
            accs[nt] = acc;
        }
        __syncthreads();
#pragma unroll
        for (int nt = 0; nt < 3; nt++)
#pragma unroll
            for (int rr = 0; rr < 4; rr++)
                exch[(rb + nt * 16 + l15) * 24 + kg * 4 + rr] = f2bf(accs[nt][rr] + bsv[nt]);
        __syncthreads();
        for (int i = threadIdx.x; i < 384; i += 256) {
            int r = i >> 1, hh = i & 1;
            *(uint4*)(on + (size_t)r * 1600 + tvb + mt * 16 + hh * 8) =
                *(const uint4*)&exch[r * 24 + hh * 8];
        }
    }
}

// -------- att_s (MFMA) -> attS_bf[n][32v][96k] bf16, k=s*25+u, pads zeroed --------
__global__ __launch_bounds__(256) void att_s_mfma(
    const ushort* __restrict__ qk, const float* __restrict__ alphas,
    const float* __restrict__ att0, ushort* __restrict__ attS_bf)
{
    __shared__ __align__(16) ushort Qs[32 * 520];
    __shared__ __align__(16) ushort Ks[32 * 520];
    const int s = blockIdx.x, n = blockIdx.y;
    const ushort* qb = qk + (size_t)n * 307200 + (size_t)(s * 32) * 1600;
    const ushort* kb = qb + 96 * 1600;
    // zero pad region (benign same-value race across the 3 s-blocks of this n)
    for (int i = threadIdx.x; i < 3072; i += 256) {
        int v = i / 96, k = i - v * 96;
        if (v >= 25 || k >= 75) attS_bf[(size_t)n * 3072 + i] = 0;
    }
    const int lane = threadIdx.x & 63, wave = threadIdx.x >> 6;
    const int l15 = lane & 15, kg = lane >> 4;
    const int mt = wave >> 1, nt = wave & 1;
    f32x4 acc = {0.f, 0.f, 0.f, 0.f};
    for (int rc = 0; rc < 4; rc++) {
        __syncthreads();
        for (int i = threadIdx.x; i < 6400; i += 256) {
            int rl = i / 800, j = i - rl * 800;
            uint uq = *(const uint*)(qb + (rc * 8 + rl) * 1600 + j * 2);
            uint uk = *(const uint*)(kb + (rc * 8 + rl) * 1600 + j * 2);
            int tv = j * 2;
            int t0 = tv / 25, u0 = tv - t0 * 25;
            int t1 = (tv + 1) / 25, u1 = (tv + 1) - t1 * 25;
            Qs[u0 * 520 + rl * 64 + t0] = (ushort)(uq & 0xffffu);
            Qs[u1 * 520 + rl * 64 + t1] = (ushort)(uq >> 16);
            Ks[u0 * 520 + rl * 64 + t0] = (ushort)(uk & 0xffffu);
            Ks[u1 * 520 + rl * 64 + t1] = (ushort)(uk >> 16);
        }
        __syncthreads();
#pragma unroll
        for (int ks = 0; ks < 16; ks++) {
            short8v a = *(const short8v*)&Qs[(mt * 16 + l15) * 520 + ks * 32 + kg * 8];
            short8v b = *(const short8v*)&Ks[(nt * 16 + l15) * 520 + ks * 32 + kg * 8];
            acc = __builtin_amdgcn_mfma_f32_16x16x32_bf16(a, b, acc, 0, 0, 0);
        }
    }
    float alpha = alphas[s];
#pragma unroll
    for (int rr = 0; rr < 4; rr++) {
        int u = mt * 16 + kg * 4 + rr, v = nt * 16 + l15;
        if (u < 25 && v < 25)
            attS_bf[(size_t)n * 3072 + v * 96 + s * 25 + u] =
                f2bf(tanhf(acc[rr] * (1.0f / 2048.0f)) * alpha + att0[s * 625 + u * 25 + v]);
    }
}

// -------- att_t (MFMA) -> attT_bf[n][64q][192k] bf16, k=s*64+t --------
__global__ __launch_bounds__(256) void att_t_mfma(
    const ushort* __restrict__ qk, const float* __restrict__ alphat,
    const float* __restrict__ att0, ushort* __restrict__ attT_bf)
{
    __shared__ __align__(16) ushort Qt[8 * 64 * 40];
    __shared__ __align__(16) ushort Kt[8 * 64 * 40];
    const int s = blockIdx.x, n = blockIdx.y;
    const ushort* qb = qk + (size_t)n * 307200 + (size_t)(s * 32) * 1600;
    const ushort* kb = qb + 96 * 1600;
    for (int i = threadIdx.x; i < 10240; i += 256) {
        ((uint*)Qt)[i] = 0u;
        ((uint*)Kt)[i] = 0u;
    }
    const int lane = threadIdx.x & 63, wave = threadIdx.x >> 6;
    const int l15 = lane & 15, kg = lane >> 4;
    const int mt = wave;
    f32x4 acc[4];
#pragma unroll
    for (int i = 0; i < 4; i++) acc[i] = (f32x4){0.f, 0.f, 0.f, 0.f};
    for (int rc = 0; rc < 4; rc++) {
        __syncthreads();
        for (int i = threadIdx.x; i < 6400; i += 256) {
            int rl = i / 800, j = i - rl * 800;
            uint uq = *(const uint*)(qb + (rc * 8 + rl) * 1600 + j * 2);
            uint uk = *(const uint*)(kb + (rc * 8 + rl) * 1600 + j * 2);
            int tv = j * 2;
            int t0 = tv / 25, v0 = tv - t0 * 25;
            int t1 = (tv + 1) / 25, v1 = (tv + 1) - t1 * 25;
            Qt[(rl * 64 + t0) * 40 + v0] = (ushort)(uq & 0xffffu);
            Qt[(rl * 64 + t1) * 40 + v1] = (ushort)(uq >> 16);
            Kt[(rl * 64 + t0) * 40 + v0] = (ushort)(uk & 0xffffu);
            Kt[(rl * 64 + t1) * 40 + v1] = (ushort)(uk >> 16);
        }
        __syncthreads();
#pragma unroll
        for (int rl = 0; rl < 8; rl++) {
            short8v a = *(const short8v*)&Qt[(rl * 64 + mt * 16 + l15) * 40 + kg * 8];
#pragma unroll
            for (int nq = 0; nq < 4; nq++) {
                short8v b = *(const short8v*)&Kt[(rl * 64 + nq * 16 + l15) * 40 + kg * 8];
                acc[nq] = __builtin_amdgcn_mfma_f32_16x16x32_bf16(a, b, acc[nq], 0, 0, 0);
            }
        }
    }
    float alpha = alphat[s];
#pragma unroll
    for (int nq = 0; nq < 4; nq++) {
        int q = nq * 16 + l15;
        ushort w4[4];
#pragma unroll
        for (int rr = 0; rr < 4; rr++) {
            int t = mt * 16 + kg * 4 + rr;
            w4[rr] = f2bf(tanhf(acc[nq][rr] * (1.0f / 800.0f)) * alpha +
                          att0[s * 4096 + t * 64 + q]);
        }
        uint2 pk;
        pk.x = (uint)w4[0] | ((uint)w4[1] << 16);
        pk.y = (uint)w4[2] | ((uint)w4[3] << 16);
        *(uint2*)(attT_bf + (size_t)n * 12288 + q * 192 + s * 64 + mt * 16 + kg * 4) = pk;
    }
}

// ------- t1 (MFMA): G[np][s][t][v][128o] bf16 = sum_c Wbf[s][o][c] * src[c][tv] -------
__global__ __launch_bounds__(256) void t1_mfma(
    const float* __restrict__ src, const ushort* __restrict__ Wbf,
    ushort* __restrict__ G)
{
    __shared__ __align__(16) ushort xT[160 * 136];
    __shared__ __align__(16) ushort Ws[128 * 136];
    const int np = blockIdx.y, tvb = blockIdx.x * 160;
    const float* sn = src + (size_t)np * 204800;
    for (int i = threadIdx.x; i < 2560; i += 256) {
        int tv4 = i % 40, cp = i / 40;
        float4 a = *(const float4*)(sn + (2 * cp) * 1600 + tvb + tv4 * 4);
        float4 b = *(const float4*)(sn + (2 * cp + 1) * 1600 + tvb + tv4 * 4);
        float av[4] = { a.x, a.y, a.z, a.w };
        float bv[4] = { b.x, b.y, b.z, b.w };
#pragma unroll
        for (int e = 0; e < 4; e++) {
            uint p = (uint)f2bf(av[e]) | ((uint)f2bf(bv[e]) << 16);
            ((uint*)xT)[(tv4 * 4 + e) * 68 + cp] = p;
        }
    }
    __syncthreads();
    const int lane = threadIdx.x & 63, wave = threadIdx.x >> 6;
    const int l15 = lane & 15, kg = lane >> 4;
    const int o_base = wave * 32;
    for (int s = 0; s < 3; s++) {
        for (int i = threadIdx.x; i < 2048; i += 256) {
            int o = i >> 4, seg = i & 15;
            uint4 wv = *(const uint4*)(Wbf + s * 16384 + o * 128 + seg * 8);
            *(uint4*)&Ws[o * 136 + seg * 8] = wv;
        }
        __syncthreads();
        short8v bfr[2][4];
#pragma unroll
        for (int nt = 0; nt < 2; nt++)
#pragma unroll
            for (int k = 0; k < 4; k++)
                bfr[nt][k] = *(short8v*)&Ws[(o_base + nt * 16 + l15) * 136 + k * 32 + kg * 8];
        ushort* Gs = G + (size_t)(np * 3 + s) * 64 * 3200;
        for (int mt = 0; mt < 10; mt++) {
            short8v af[4];
#pragma unroll
            for (int k = 0; k < 4; k++)
                af[k] = *(short8v*)&xT[(mt * 16 + l15) * 136 + k * 32 + kg * 8];
            f32x4 acc0 = {0.f, 0.f, 0.f, 0.f};
            f32x4 acc1 = {0.f, 0.f, 0.f, 0.f};
#pragma unroll
            for (int k = 0; k < 4; k++) {
                acc0 = __builtin_amdgcn_mfma_f32_16x16x32_bf16(af[k], bfr[0][k], acc0, 0, 0, 0);
                acc1 = __builtin_amdgcn_mfma_f32_16x16x32_bf16(af[k], bfr[1][k], acc1, 0, 0, 0);
            }
#pragma unroll
            for (int r = 0; r < 4; r++) {
                int tvg = tvb + mt * 16 + kg * 4 + r;
                int t = tvg / 25, v = tvg - t * 25;
                Gs[t * 3200 + v * 128 + o_base + l15]      = f2bf(acc0[r]);
                Gs[t * 3200 + v * 128 + o_base + 16 + l15] = f2bf(acc1[r]);
            }
        }
        __syncthreads();
    }
}

// ------- s2 (MFMA): pre[tv][128o] = BN( sum_{su} attS_bf[v][su] * H[su][(t,o)] ) -------
__global__ __launch_bounds__(256) void s2_mfma(
    const ushort* __restrict__ H, const ushort* __restrict__ attS,
    const float* __restrict__ bnp, const float* __restrict__ bo,
    ushort* __restrict__ pre)
{
    __shared__ __align__(16) ushort Bt[256 * 128]; // [n=tl*128+o][k swz], stride 128
    __shared__ float sc_l[128], of_l[128];
    const int np = blockIdx.y, t0 = blockIdx.x * 2;
    if (threadIdx.x < 128) {
        int o = threadIdx.x;
        float sc = bnp[o] * rsqrtf(bnp[384 + o] + 1e-5f);
        sc_l[o] = sc;
        of_l[o] = (bo[o] - bnp[256 + o]) * sc + bnp[128 + o];
    }
    const int lane = threadIdx.x & 63, wave = threadIdx.x >> 6;
    const int l15 = lane & 15, kg = lane >> 4;
    const ushort* An = attS + (size_t)np * 3072;
    short8v a[2][3];
#pragma unroll
    for (int mt = 0; mt < 2; mt++)
#pragma unroll
        for (int ks = 0; ks < 3; ks++)
            a[mt][ks] = *(const short8v*)(An + (mt * 16 + l15) * 96 + ks * 32 + kg * 8);
    // zero K-pad cols 75..95
    for (int i = threadIdx.x; i < 5376; i += 256) {
        int n = i / 21, k = 75 + i % 21;
        Bt[n * 128 + (((k >> 3) ^ ((n >> 1) & 7)) << 3) + (k & 7)] = 0;
    }
    // stage: H[s][t0+tl][u][o] -> Bt[tl*128+o][s*25+u]
    const ushort* Hq = H + (size_t)np * 192 * 3200;
    for (int i = threadIdx.x; i < 9600; i += 256) {
        int op = i & 63, row = i >> 6;
        int s = row / 50, r2 = row - s * 50, tl = r2 / 25, u = r2 - tl * 25;
        uint w = *(const uint*)(Hq + (s * 64 + t0 + tl) * 3200 + u * 128 + op * 2);
        int k = s * 25 + u;
        int n0 = tl * 128 + op * 2;
        int base = n0 * 128 + (((k >> 3) ^ ((n0 >> 1) & 7)) << 3) + (k & 7);
        Bt[base]       = (ushort)(w & 0xffffu);
        Bt[base + 128] = (ushort)(w >> 16);
    }
    __syncthreads();
    f32x4 acc[2][4];
#pragma unroll
    for (int mt = 0; mt < 2; mt++)
#pragma unroll
        for (int jj = 0; jj < 4; jj++) acc[mt][jj] = (f32x4){0.f, 0.f, 0.f, 0.f};
    const int jb = wave * 4;
#pragma unroll
    for (int ks = 0; ks < 3; ks++) {
        short8v b[4];
#pragma unroll
        for (int jj = 0; jj < 4; jj++) {
            int n = (jb + jj) * 16 + l15;
            b[jj] = *(const short8v*)&Bt[n * 128 + ((((ks * 4 + kg) ^ ((n >> 1) & 7))) << 3)];
        }
#pragma unroll
        for (int mt = 0; mt < 2; mt++)
#pragma unroll
            for (int jj = 0; jj < 4; jj++)
                acc[mt][jj] = __builtin_amdgcn_mfma_f32_16x16x32_bf16(a[mt][ks], b[jj], acc[mt][jj], 0, 0, 0);
    }
    ushort* pq = pre + (size_t)np * 204800;
#pragma unroll
    for (int mt = 0; mt < 2; mt++)
#pragma unroll
        for (int jj = 0; jj < 4; jj++) {
            int n = (jb + jj) * 16 + l15;
            int tl = n >> 7, o = n & 127;
            float sc = sc_l[o], of = of_l[o];
#pragma unroll
            for (int rr = 0; rr < 4; rr++) {
                int v = mt * 16 + kg * 4 + rr;
                if (v < 25)
                    pq[((t0 + tl) * 25 + v) * 128 + o] = f2bf(acc[mt][jj][rr] * sc + of);
            }
        }
}

// ------- t2 (MFMA): pre[(q*25+v)][128o] = BN( sum_{st} attT_bf[q][st] * G[st][v][o] ) -------
__global__ __launch_bounds__(256) void t2_mfma(
    const ushort* __restrict__ G, const ushort* __restrict__ attT,
    const float* __restrict__ bnp, const float* __restrict__ bo,
    ushort* __restrict__ pre)
{
    __shared__ __align__(16) ushort Bt[128 * 256]; // [o][k swz], stride 256
    __shared__ float sc_l[128], of_l[128];
    const int v = blockIdx.x, np = blockIdx.y;
    if (threadIdx.x < 128) {
        int o = threadIdx.x;
        float sc = bnp[o] * rsqrtf(bnp[384 + o] + 1e-5f);
        sc_l[o] = sc;
        of_l[o] = (bo[o] - bnp[256 + o]) * sc + bnp[128 + o];
    }
    const int lane = threadIdx.x & 63, wave = threadIdx.x >> 6;
    const int l15 = lane & 15, kg = lane >> 4;
    const ushort* An = attT + (size_t)np * 12288;
    short8v a[4][6];
#pragma unroll
    for (int mt = 0; mt < 4; mt++)
#pragma unroll
        for (int ks = 0; ks < 6; ks++)
            a[mt][ks] = *(const short8v*)(An + (mt * 16 + l15) * 192 + ks * 32 + kg * 8);
    const ushort* Gq = G + (size_t)np * 192 * 3200 + v * 128;
    for (int i = threadIdx.x; i < 12288; i += 256) {
        int op = i & 63, st = i >> 6;
        uint w = *(const uint*)(Gq + st * 3200 + op * 2);
        int o0 = op * 2;
        int base = o0 * 256 + (((st >> 3) ^ ((o0 >> 1) & 7)) << 3) + (st & 7);
        Bt[base]       = (ushort)(w & 0xffffu);
        Bt[base + 256] = (ushort)(w >> 16);
    }
    __syncthreads();
    f32x4 acc[4][2];
#pragma unroll
    for (int mt = 0; mt < 4; mt++)
#pragma unroll
        for (int jj = 0; jj < 2; jj++) acc[mt][jj] = (f32x4){0.f, 0.f, 0.f, 0.f};
    const int jb = wave * 2;
#pragma unroll
    for (int ks = 0; ks < 6; ks++) {
        short8v b[2];
#pragma unroll
        for (int jj = 0; jj < 2; jj++) {
            int o = (jb + jj) * 16 + l15;
            b[jj] = *(const short8v*)&Bt[o * 256 + ((((ks * 4 + kg) ^ ((o >> 1) & 7))) << 3)];
        }
#pragma unroll
        for (int mt = 0; mt < 4; mt++)
#pragma unroll
            for (int jj = 0; jj < 2; jj++)
                acc[mt][jj] = __builtin_amdgcn_mfma_f32_16x16x32_bf16(a[mt][ks], b[jj], acc[mt][jj], 0, 0, 0);
    }
    ushort* pq = pre + (size_t)np * 204800;
#pragma unroll
    for (int mt = 0; mt < 4; mt++)
#pragma unroll
        for (int jj = 0; jj < 2; jj++) {
            int o = (jb + jj) * 16 + l15;
            float sc = sc_l[o], of = of_l[o];
#pragma unroll
            for (int rr = 0; rr < 4; rr++) {
                int q = mt * 16 + kg * 4 + rr;
                pq[(q * 25 + v) * 128 + o] = f2bf(acc[mt][jj][rr] * sc + of);
            }
        }
}

// ------- cbr (MFMA): out = lrelu(res + BN2(Wf @ lrelu(res + pre) + b)) -------
__global__ __launch_bounds__(256) void cbr_mfma(
    const ushort* __restrict__ pre, const float* res,
    const ushort* __restrict__ Wbf, const float* __restrict__ bias,
    const float* __restrict__ bnp, float* outp)
{
    __shared__ __align__(16) ushort xT[160 * 136];
    __shared__ float sc_l[128], of_l[128];
    const int np = blockIdx.y, tvb = blockIdx.x * 160;
    if (threadIdx.x < 128) {
        int o = threadIdx.x;
        float sc = bnp[o] * rsqrtf(bnp[384 + o] + 1e-5f);
        sc_l[o] = sc;
        of_l[o] = (bias[o] - bnp[256 + o]) * sc + bnp[128 + o];
    }
    // phase 1: linear copy pre tile -> xT[tv][c]
    const ushort* pp = pre + (size_t)np * 204800 + (size_t)tvb * 128;
    for (int i = threadIdx.x; i < 10240; i += 256) {
        int tl = i >> 6, cp = i & 63;
        ((uint*)xT)[tl * 68 + cp] = *(const uint*)(pp + tl * 128 + cp * 2);
    }
    __syncthreads();
    // phase 2: y1 = lrelu(res + pre)
    const float* rq = res + (size_t)np * 204800;
    for (int i = threadIdx.x; i < 5120; i += 256) {
        int tv = i % 160, cq = i / 160, c = cq * 4;
        uint2 w = *(uint2*)&xT[tv * 136 + c];
        float h0 = rq[(size_t)(c + 0) * 1600 + tvb + tv] + bf2f((ushort)(w.x & 0xffffu));
        float h1 = rq[(size_t)(c + 1) * 1600 + tvb + tv] + bf2f((ushort)(w.x >> 16));
        float h2 = rq[(size_t)(c + 2) * 1600 + tvb + tv] + bf2f((ushort)(w.y & 0xffffu));
        float h3 = rq[(size_t)(c + 3) * 1600 + tvb + tv] + bf2f((ushort)(w.y >> 16));
        h0 = h0 > 0.f ? h0 : 0.1f * h0;
        h1 = h1 > 0.f ? h1 : 0.1f * h1;
        h2 = h2 > 0.f ? h2 : 0.1f * h2;
        h3 = h3 > 0.f ? h3 : 0.1f * h3;
        w.x = (uint)f2bf(h0) | ((uint)f2bf(h1) << 16);
        w.y = (uint)f2bf(h2) | ((uint)f2bf(h3) << 16);
        *(uint2*)&xT[tv * 136 + c] = w;
    }
    __syncthreads();
    const int lane = threadIdx.x & 63, wave = threadIdx.x >> 6;
    const int l15 = lane & 15, kg = lane >> 4;
    const int ob = wave * 32;
    short8v af[2][4];
#pragma unroll
    for (int mt = 0; mt < 2; mt++)
#pragma unroll
        for (int k = 0; k < 4; k++)
            af[mt][k] = *(const short8v*)&Wbf[(ob + mt * 16 + l15) * 128 + k * 32 + kg * 8];
    for (int nt = 0; nt < 10; nt++) {
        short8v bfg[4];
#pragma unroll
        for (int k = 0; k < 4; k++)
            bfg[k] = *(short8v*)&xT[(nt * 16 + l15) * 136 + k * 32 + kg * 8];
        f32x4 acc0 = {0.f, 0.f, 0.f, 0.f};
        f32x4 acc1 = {0.f, 0.f, 0.f, 0.f};
#pragma unroll
        for (int k = 0; k < 4; k++) {
            acc0 = __builtin_amdgcn_mfma_f32_16x16x32_bf16(af[0][k], bfg[k], acc0, 0, 0, 0);
            acc1 = __builtin_amdgcn_mfma_f32_16x16x32_bf16(af[1][k], bfg[k], acc1, 0, 0, 0);
        }
        int tv = tvb + nt * 16 + l15;
#pragma unroll
        for (int rr = 0; rr < 4; rr++) {
            {
                int o = ob + kg * 4 + rr;
                size_t idx = (size_t)np * 204800 + (size_t)o * 1600 + tv;
                float h = acc0[rr] * sc_l[o] + of_l[o] + res[idx];
                outp[idx] = h > 0.f ? h : 0.1f * h;
            }
            {
                int o = ob + 16 + kg * 4 + rr;
                size_t idx = (size_t)np * 204800 + (size_t)o * 1600 + tv;
                float h = acc1[rr] * sc_l[o] + of_l[o] + res[idx];
                outp[idx] = h > 0.f ? h : 0.1f * h;
            }
        }
    }
}

extern "C" void kernel_launch(void* const* d_in, const int* in_sizes, int n_in,
                              void* d_out, int out_size, void* d_ws, size_t ws_size,
                              hipStream_t stream)
{
    (void)in_sizes; (void)n_in; (void)out_size; (void)ws_size;
    const float* x      = (const float*)d_in[0];
    const float* Wqk_s  = (const float*)d_in[1];
    const float* bqk_s  = (const float*)d_in[2];
    const float* alphas = (const float*)d_in[3];
    const float* att0s  = (const float*)d_in[4];
    const float* Wo_s   = (const float*)d_in[5];
    const float* bo_s   = (const float*)d_in[6];
    const float* bn_o_s = (const float*)d_in[7];
    const float* Wf_s   = (const float*)d_in[8];
    const float* bf_s   = (const float*)d_in[9];
    const float* bn_f_s = (const float*)d_in[10];
    const float* Wqk_t  = (const float*)d_in[11];
    const float* bqk_t  = (const float*)d_in[12];
    const float* alphat = (const float*)d_in[13];
    const float* att0t  = (const float*)d_in[14];
    const float* Wo_t   = (const float*)d_in[15];
    const float* bo_t   = (const float*)d_in[16];
    const float* bn_o_t = (const float*)d_in[17];
    const float* Wf_t   = (const float*)d_in[18];
    const float* bf_t   = (const float*)d_in[19];
    const float* bn_f_t = (const float*)d_in[20];

    float* out = (float*)d_out;
    const size_t CTV = 204800;
    // ws layout (bytes):
    //  [0, 78,643,200)   qk bf16 [n][192][1600] — reused per quarter:
    //      G/H = [0, 39,321,600) ; pre = [39,321,600, 52,428,800)
    //  [78,643,200, 79,429,632)  attS_bf [128n][32][96] bf16
    //  [79,603,200, 82,748,928)  attT_bf [128n][64][192] bf16
    //  [85,894,656, 86,255,104)  W16 bf16 weights
    ushort* qk      = (ushort*)d_ws;
    ushort* Gbuf    = (ushort*)d_ws;
    ushort* pre     = (ushort*)((char*)d_ws + 39321600);
    ushort* attS_bf = (ushort*)((char*)d_ws + 78643200);
    ushort* attT_bf = (ushort*)((char*)d_ws + 79603200);
    ushort* W16     = (ushort*)((char*)d_ws + 85894656);
    const ushort* WoS_bf  = W16;
    const ushort* WfS_bf  = W16 + 49152;
    const ushort* WoT_bf  = W16 + 65536;
    const ushort* WfT_bf  = W16 + 114688;
    const ushort* WqkS_bf = W16 + 131072;
    const ushort* WqkT_bf = W16 + 155648;

    wt_prep<<<704, 256, 0, stream>>>(Wo_s, Wf_s, Wo_t, Wf_t, Wqk_s, Wqk_t, W16);

    dim3 gqk(10, 128), gatt(3, 128), gt1(10, 32), gs2(32, 32), gt2(25, 32), gcbr(10, 32);

    // ---- spatial ----
    qk_pe_mfma<<<gqk, 256, 0, stream>>>(x, WqkS_bf, bqk_s, qk, 0);
    att_s_mfma<<<gatt, 256, 0, stream>>>(qk, alphas, att0s, attS_bf);
    for (int h = 0; h < 4; h++) {
        size_t n0 = (size_t)h * 32;
        t1_mfma<<<gt1, 256, 0, stream>>>(x + n0 * CTV, WoS_bf, Gbuf);
        s2_mfma<<<gs2, 256, 0, stream>>>(Gbuf, attS_bf + n0 * 3072, bn_o_s, bo_s, pre);
        cbr_mfma<<<gcbr, 256, 0, stream>>>(pre, x + n0 * CTV, WfS_bf, bf_s, bn_f_s,
                                           out + n0 * CTV);
    }

    // ---- temporal ----
    qk_pe_mfma<<<gqk, 256, 0, stream>>>(out, WqkT_bf, bqk_t, qk, 1);
    att_t_mfma<<<gatt, 256, 0, stream>>>(qk, alphat, att0t, attT_bf);
    for (int h = 0; h < 4; h++) {
        size_t n0 = (size_t)h * 32;
        t1_mfma<<<gt1, 256, 0, stream>>>(out + n0 * CTV, WoT_bf, Gbuf);
        t2_mfma<<<gt2, 256, 0, stream>>>(Gbuf, attT_bf + n0 * 12288, bn_o_t, bo_t, pre);
        cbr_mfma<<<gcbr, 256, 0, stream>>>(pre, out + n0 * CTV, WfT_bf, bf_t, bn_f_t,
                                           out + n0 * CTV);
    }
}